// Round 1
// baseline (964.814 us; speedup 1.0000x reference)
//
#include <hip/hip_runtime.h>
#include <hip/hip_bf16.h>

// ---------------- problem constants (from reference) ----------------
// N = 100000 nodes, E = 1600000 edges, F_IN = 512, H1*C1 = 64, NUM_CLASSES = 40
#define F_IN 512
#define HC1 64          // 8 heads * 8 ch
#define NH1 8
#define NC 40
#define NEG_SLOPE 0.2f
#define SCAN_CHUNK 2048

// ---------------- edge-index normalization ----------------
// Detect whether edge_index buffer is int64 (JAX x64 on) or int32 (x64 off).
// int64 layout: little-endian, high word of every element == 0 (values < 2^31).
__global__ void detect_i64(const int* __restrict__ ei, int* __restrict__ flag, int n_check) {
    __shared__ int found;
    if (threadIdx.x == 0) found = 0;
    __syncthreads();
    for (int i = threadIdx.x; i < n_check; i += 256) {
        if (ei[2 * i + 1] != 0) atomicOr(&found, 1);
    }
    __syncthreads();
    if (threadIdx.x == 0) *flag = (found == 0) ? 1 : 0;   // 1 => int64
}

__global__ void normalize_edges(const int* __restrict__ ei, const int* __restrict__ flag,
                                int* __restrict__ srcw, int* __restrict__ dstw, int E) {
    int e = blockIdx.x * 256 + threadIdx.x;
    if (e >= E) return;
    int f = *flag;
    if (f) { srcw[e] = ei[2 * e]; dstw[e] = ei[2 * (E + e)]; }
    else   { srcw[e] = ei[e];     dstw[e] = ei[E + e]; }
}

// ---------------- CSR build ----------------
__global__ void hist_kernel(const int* __restrict__ dstw, int* __restrict__ deg, int E) {
    int e = blockIdx.x * 256 + threadIdx.x;
    if (e < E) atomicAdd(&deg[dstw[e]], 1);
}

// pass 1: per-chunk (2048) inclusive scan, chunk sums out
__global__ __launch_bounds__(256) void scan1(const int* __restrict__ deg, int* __restrict__ rowptr,
                                             int* __restrict__ bsums, int n) {
    __shared__ int sbuf[256];
    int tid = threadIdx.x;
    int base = blockIdx.x * SCAN_CHUNK + tid * 8;
    int v[8];
#pragma unroll
    for (int j = 0; j < 8; j++) { int idx = base + j; v[j] = (idx < n) ? deg[idx] : 0; }
    int tsum = 0;
#pragma unroll
    for (int j = 0; j < 8; j++) tsum += v[j];
    sbuf[tid] = tsum;
    __syncthreads();
    for (int off = 1; off < 256; off <<= 1) {
        int t = (tid >= off) ? sbuf[tid - off] : 0;
        __syncthreads();
        sbuf[tid] += t;
        __syncthreads();
    }
    int run = sbuf[tid] - tsum;   // exclusive prefix of this thread
#pragma unroll
    for (int j = 0; j < 8; j++) {
        run += v[j];
        int idx = base + j;
        if (idx < n) rowptr[1 + idx] = run;   // temp: inclusive within chunk
    }
    if (tid == 255) bsums[blockIdx.x] = sbuf[255];
}

// pass 2: exclusive scan of <=64 chunk sums in one wave
__global__ void scan2(int* __restrict__ bsums, int nb) {
    int lane = threadIdx.x & 63;
    int v = (lane < nb) ? bsums[lane] : 0;
    int orig = v;
    for (int off = 1; off < 64; off <<= 1) {
        int t = __shfl_up(v, (unsigned)off, 64);
        if (lane >= off) v += t;
    }
    if (lane < nb) bsums[lane] = v - orig;   // exclusive
}

// pass 3: finalize rowptr, init cursor
__global__ void scan3(const int* __restrict__ deg, int* __restrict__ rowptr,
                      int* __restrict__ cursor, const int* __restrict__ bsums, int n) {
    int i = blockIdx.x * 256 + threadIdx.x;
    if (i >= n) return;
    int off = bsums[i >> 11];
    int incl = rowptr[1 + i] + off;
    rowptr[1 + i] = incl;
    cursor[i] = incl - deg[i];
    if (i == 0) rowptr[0] = 0;
}

__global__ void scatter_kernel(const int* __restrict__ srcw, const int* __restrict__ dstw,
                               int* __restrict__ cursor, int* __restrict__ col, int E) {
    int e = blockIdx.x * 256 + threadIdx.x;
    if (e < E) {
        int pos = atomicAdd(&cursor[dstw[e]], 1);
        col[pos] = srcw[e];
    }
}

// ---------------- GEMM1: h1[N,64] = x[N,512] @ W1[512,64] ----------------
// 64-row tile, all 64 cols, K chunks of 32, fp32, 256 threads, 4x4 micro-tile.
__global__ __launch_bounds__(256) void gemm1(const float* __restrict__ x, const float* __restrict__ W,
                                             float* __restrict__ h1, int Nn) {
    __shared__ __align__(16) float xsT[32][68];   // [k][m], padded to keep 16B alignment
    __shared__ __align__(16) float ws[32][64];    // [k][n]
    int tid = threadIdx.x;
    int m0 = blockIdx.x * 64;
    int tx = tid & 15, ty = tid >> 4;
    float acc[4][4] = {{0.f}};

    int lr = tid >> 2;            // 0..63 : row within tile
    int lk = (tid & 3) * 8;       // 0,8,16,24 : k offset
    int wrow = tid >> 3;          // 0..31
    int wcol = (tid & 7) * 8;     // 0..56
    bool rowok = (m0 + lr) < Nn;
    const float* xrow = x + (size_t)(m0 + lr) * F_IN;

    for (int k0 = 0; k0 < F_IN; k0 += 32) {
        float4 a0 = make_float4(0.f, 0.f, 0.f, 0.f), a1 = a0;
        if (rowok) {
            a0 = *(const float4*)(xrow + k0 + lk);
            a1 = *(const float4*)(xrow + k0 + lk + 4);
        }
        float4 b0 = *(const float4*)(W + (size_t)(k0 + wrow) * HC1 + wcol);
        float4 b1 = *(const float4*)(W + (size_t)(k0 + wrow) * HC1 + wcol + 4);
        __syncthreads();
        xsT[lk + 0][lr] = a0.x; xsT[lk + 1][lr] = a0.y;
        xsT[lk + 2][lr] = a0.z; xsT[lk + 3][lr] = a0.w;
        xsT[lk + 4][lr] = a1.x; xsT[lk + 5][lr] = a1.y;
        xsT[lk + 6][lr] = a1.z; xsT[lk + 7][lr] = a1.w;
        *(float4*)&ws[wrow][wcol] = b0;
        *(float4*)&ws[wrow][wcol + 4] = b1;
        __syncthreads();
#pragma unroll
        for (int kk = 0; kk < 32; ++kk) {
            float4 av = *(const float4*)&xsT[kk][ty * 4];
            float4 bv = *(const float4*)&ws[kk][tx * 4];
            float aa[4] = {av.x, av.y, av.z, av.w};
            float bb[4] = {bv.x, bv.y, bv.z, bv.w};
#pragma unroll
            for (int i = 0; i < 4; i++)
#pragma unroll
                for (int j = 0; j < 4; j++) acc[i][j] += aa[i] * bb[j];
        }
    }
#pragma unroll
    for (int i = 0; i < 4; i++) {
        int r = m0 + ty * 4 + i;
        if (r < Nn) {
            *(float4*)(h1 + (size_t)r * HC1 + tx * 4) =
                make_float4(acc[i][0], acc[i][1], acc[i][2], acc[i][3]);
        }
    }
}

// ---------------- alpha1: per-node per-head attention logits ----------------
__global__ void alpha1_kernel(const float* __restrict__ h1, const float* __restrict__ a_s,
                              const float* __restrict__ a_d, float* __restrict__ as1,
                              float* __restrict__ ad1, int Nn) {
    int idx = blockIdx.x * 256 + threadIdx.x;   // n*8 + h
    if (idx >= Nn * NH1) return;
    int h = idx & 7;
    const float* hp = h1 + (size_t)(idx >> 3) * HC1 + h * 8;
    float s = 0.f, d = 0.f;
#pragma unroll
    for (int c = 0; c < 8; c++) {
        float v = hp[c];
        s += v * a_s[h * 8 + c];
        d += v * a_d[h * 8 + c];
    }
    as1[idx] = s;
    ad1[idx] = d;
}

// ---------------- layer-1 aggregation: online softmax + weighted sum + bias + ELU --------
// one wave per dst node; lane = h*8 + c
__global__ __launch_bounds__(256) void agg1(const float* __restrict__ h1, const float* __restrict__ as1,
                                            const float* __restrict__ ad1, const int* __restrict__ rowptr,
                                            const int* __restrict__ col, const float* __restrict__ b1,
                                            float* __restrict__ h2, int Nn) {
    int wave = (blockIdx.x * 256 + threadIdx.x) >> 6;
    int lane = threadIdx.x & 63;
    if (wave >= Nn) return;
    int d = wave;
    int h = lane >> 3;
    float adv = ad1[d * NH1 + h];
    // self loop init
    float e0 = as1[d * NH1 + h] + adv;
    e0 = e0 > 0.f ? e0 : NEG_SLOPE * e0;
    float m = e0, s = 1.0f;
    float acc = h1[(size_t)d * HC1 + lane];
    int jb = rowptr[d], je = rowptr[d + 1];
    for (int j = jb; j < je; j++) {
        int src = col[j];
        float e = as1[src * NH1 + h] + adv;
        e = e > 0.f ? e : NEG_SLOPE * e;
        float mn = fmaxf(m, e);
        float corr = __expf(m - mn);
        float p = __expf(e - mn);
        s = s * corr + p;
        acc = acc * corr + p * h1[(size_t)src * HC1 + lane];
        m = mn;
    }
    float o = acc / (s + 1e-16f) + b1[lane];
    o = o > 0.f ? o : __expf(o) - 1.0f;     // ELU
    h2[(size_t)d * HC1 + lane] = o;
}

// ---------------- GEMM2 + alpha2: g[N,40] = h2[N,64] @ W2[64,40]; as2/ad2 dots --------
__global__ __launch_bounds__(256) void gemm2(const float* __restrict__ h2, const float* __restrict__ W2,
                                             const float* __restrict__ av_in, const float* __restrict__ dv_in,
                                             float* __restrict__ g, float* __restrict__ as2,
                                             float* __restrict__ ad2, int Nn) {
    __shared__ float W2s[HC1 * NC];
    __shared__ float hrow[4][HC1];
    __shared__ float avec[NC], dvec[NC];
    int tid = threadIdx.x;
    for (int i = tid; i < HC1 * NC; i += 256) W2s[i] = W2[i];
    if (tid < NC) { avec[tid] = av_in[tid]; dvec[tid] = dv_in[tid]; }
    int w = tid >> 6, lane = tid & 63;
    int n = blockIdx.x * 4 + w;
    float hv = 0.f;
    if (n < Nn) hv = h2[(size_t)n * HC1 + lane];
    hrow[w][lane] = hv;
    __syncthreads();
    float acc = 0.f;
    bool act = (n < Nn) && (lane < NC);
    if (act) {
#pragma unroll
        for (int k = 0; k < HC1; k++) acc += hrow[w][k] * W2s[k * NC + lane];
        g[(size_t)n * NC + lane] = acc;
    }
    float va = act ? acc * avec[lane] : 0.f;
    float vd = act ? acc * dvec[lane] : 0.f;
    for (int off = 32; off; off >>= 1) {
        va += __shfl_xor(va, off, 64);
        vd += __shfl_xor(vd, off, 64);
    }
    if (n < Nn && lane == 0) { as2[n] = va; ad2[n] = vd; }
}

// ---------------- layer-2 aggregation + bias + log_softmax ----------------
__global__ __launch_bounds__(256) void agg2(const float* __restrict__ g, const float* __restrict__ as2,
                                            const float* __restrict__ ad2, const int* __restrict__ rowptr,
                                            const int* __restrict__ col, const float* __restrict__ b2,
                                            float* __restrict__ out, int Nn) {
    int wave = (blockIdx.x * 256 + threadIdx.x) >> 6;
    int lane = threadIdx.x & 63;
    if (wave >= Nn) return;
    int d = wave;
    float adv = ad2[d];
    float e0 = as2[d] + adv;
    e0 = e0 > 0.f ? e0 : NEG_SLOPE * e0;
    float m = e0, s = 1.0f;
    float acc = (lane < NC) ? g[(size_t)d * NC + lane] : 0.f;
    int jb = rowptr[d], je = rowptr[d + 1];
    for (int j = jb; j < je; j++) {
        int src = col[j];
        float e = as2[src] + adv;
        e = e > 0.f ? e : NEG_SLOPE * e;
        float mn = fmaxf(m, e);
        float corr = __expf(m - mn);
        float p = __expf(e - mn);
        s = s * corr + p;
        float gv = (lane < NC) ? g[(size_t)src * NC + lane] : 0.f;
        acc = acc * corr + p * gv;
        m = mn;
    }
    float o = acc / (s + 1e-16f) + ((lane < NC) ? b2[lane] : 0.f);
    // log_softmax over lanes 0..39
    float vm = (lane < NC) ? o : -1e30f;
    for (int off = 32; off; off >>= 1) vm = fmaxf(vm, __shfl_xor(vm, off, 64));
    float ex = (lane < NC) ? __expf(o - vm) : 0.f;
    for (int off = 32; off; off >>= 1) ex += __shfl_xor(ex, off, 64);
    float lsm = o - vm - __logf(ex);
    if (lane < NC) out[(size_t)d * NC + lane] = lsm;
}

// ---------------- host launch ----------------
extern "C" void kernel_launch(void* const* d_in, const int* in_sizes, int n_in,
                              void* d_out, int out_size, void* d_ws, size_t ws_size,
                              hipStream_t stream) {
    const float* x      = (const float*)d_in[0];
    const int*   ei     = (const int*)d_in[1];
    const float* W1     = (const float*)d_in[2];
    const float* a_src1 = (const float*)d_in[3];
    const float* a_dst1 = (const float*)d_in[4];
    const float* b1     = (const float*)d_in[5];
    const float* W2     = (const float*)d_in[6];
    const float* a_src2 = (const float*)d_in[7];
    const float* a_dst2 = (const float*)d_in[8];
    const float* b2     = (const float*)d_in[9];
    float* out = (float*)d_out;

    const int N = in_sizes[0] / F_IN;       // 100000
    const int E = in_sizes[1] / 2;          // 1600000

    // workspace carve-up (256B aligned)
    char* p = (char*)d_ws;
    auto alloc = [&](size_t bytes) -> void* {
        void* r = (void*)p;
        p += (bytes + 255) & ~(size_t)255;
        return r;
    };
    int* srcw   = (int*)alloc((size_t)E * 4);
    int* dstw   = (int*)alloc((size_t)E * 4);
    int* deg    = (int*)alloc((size_t)N * 4);
    int* rowptr = (int*)alloc(((size_t)N + 1) * 4);
    int* cursor = (int*)alloc((size_t)N * 4);
    int* bsums  = (int*)alloc(64 * 4);
    int* flag   = (int*)alloc(256);
    int* col    = (int*)alloc((size_t)E * 4);
    float* h1   = (float*)alloc((size_t)N * HC1 * 4);   // reused as g (N*40 <= N*64)
    float* as1  = (float*)alloc((size_t)N * NH1 * 4);   // reused as as2
    float* ad1  = (float*)alloc((size_t)N * NH1 * 4);   // reused as ad2
    float* h2   = (float*)alloc((size_t)N * HC1 * 4);
    float* g    = h1;
    float* as2  = as1;
    float* ad2  = ad1;

    // --- edge normalization + CSR build ---
    hipMemsetAsync(deg, 0, (size_t)N * 4, stream);
    detect_i64<<<1, 256, 0, stream>>>(ei, flag, 4096);
    int ge = (E + 255) / 256;
    normalize_edges<<<ge, 256, 0, stream>>>(ei, flag, srcw, dstw, E);
    hist_kernel<<<ge, 256, 0, stream>>>(dstw, deg, E);
    int nb = (N + SCAN_CHUNK - 1) / SCAN_CHUNK;     // 49, fits in one wave
    scan1<<<nb, 256, 0, stream>>>(deg, rowptr, bsums, N);
    scan2<<<1, 64, 0, stream>>>(bsums, nb);
    scan3<<<(N + 255) / 256, 256, 0, stream>>>(deg, rowptr, cursor, bsums, N);
    scatter_kernel<<<ge, 256, 0, stream>>>(srcw, dstw, cursor, col, E);

    // --- layer 1 ---
    gemm1<<<(N + 63) / 64, 256, 0, stream>>>(x, W1, h1, N);
    alpha1_kernel<<<(N * NH1 + 255) / 256, 256, 0, stream>>>(h1, a_src1, a_dst1, as1, ad1, N);
    agg1<<<(N + 3) / 4, 256, 0, stream>>>(h1, as1, ad1, rowptr, col, b1, h2, N);

    // --- layer 2 ---
    gemm2<<<(N + 3) / 4, 256, 0, stream>>>(h2, W2, a_src2, a_dst2, g, as2, ad2, N);
    agg2<<<(N + 3) / 4, 256, 0, stream>>>(g, as2, ad2, rowptr, col, b2, out, N);
}

// Round 2
// 851.348 us; speedup vs baseline: 1.1333x; 1.1333x over previous
//
#include <hip/hip_runtime.h>
#include <hip/hip_bf16.h>

// ---------------- problem constants (from reference) ----------------
// N = 100000 nodes, E = 1600000 edges, F_IN = 512, H1*C1 = 64, NUM_CLASSES = 40
#define F_IN 512
#define HC1 64          // 8 heads * 8 ch
#define NH1 8
#define NC 40
#define NEG_SLOPE 0.2f
#define SCAN_CHUNK 2048

// ---------------- edge-index normalization ----------------
// Detect whether edge_index buffer is int64 (JAX x64 on) or int32 (x64 off).
__global__ void detect_i64(const int* __restrict__ ei, int* __restrict__ flag, int n_check) {
    __shared__ int found;
    if (threadIdx.x == 0) found = 0;
    __syncthreads();
    for (int i = threadIdx.x; i < n_check; i += 256) {
        if (ei[2 * i + 1] != 0) atomicOr(&found, 1);
    }
    __syncthreads();
    if (threadIdx.x == 0) *flag = (found == 0) ? 1 : 0;   // 1 => int64
}

// normalize + degree histogram fused (one E-pass saved)
__global__ void normalize_edges(const int* __restrict__ ei, const int* __restrict__ flag,
                                int* __restrict__ srcw, int* __restrict__ dstw,
                                int* __restrict__ deg, int E) {
    int e = blockIdx.x * 256 + threadIdx.x;
    if (e >= E) return;
    int f = *flag;
    int s, d;
    if (f) { s = ei[2 * e]; d = ei[2 * (E + e)]; }
    else   { s = ei[e];     d = ei[E + e]; }
    srcw[e] = s;
    dstw[e] = d;
    atomicAdd(&deg[d], 1);
}

// ---------------- CSR build ----------------
// pass 1: per-chunk (2048) inclusive scan, chunk sums out
__global__ __launch_bounds__(256) void scan1(const int* __restrict__ deg, int* __restrict__ rowptr,
                                             int* __restrict__ bsums, int n) {
    __shared__ int sbuf[256];
    int tid = threadIdx.x;
    int base = blockIdx.x * SCAN_CHUNK + tid * 8;
    int v[8];
#pragma unroll
    for (int j = 0; j < 8; j++) { int idx = base + j; v[j] = (idx < n) ? deg[idx] : 0; }
    int tsum = 0;
#pragma unroll
    for (int j = 0; j < 8; j++) tsum += v[j];
    sbuf[tid] = tsum;
    __syncthreads();
    for (int off = 1; off < 256; off <<= 1) {
        int t = (tid >= off) ? sbuf[tid - off] : 0;
        __syncthreads();
        sbuf[tid] += t;
        __syncthreads();
    }
    int run = sbuf[tid] - tsum;   // exclusive prefix of this thread
#pragma unroll
    for (int j = 0; j < 8; j++) {
        run += v[j];
        int idx = base + j;
        if (idx < n) rowptr[1 + idx] = run;   // temp: inclusive within chunk
    }
    if (tid == 255) bsums[blockIdx.x] = sbuf[255];
}

// pass 2: exclusive scan of <=64 chunk sums in one wave
__global__ void scan2(int* __restrict__ bsums, int nb) {
    int lane = threadIdx.x & 63;
    int v = (lane < nb) ? bsums[lane] : 0;
    int orig = v;
    for (int off = 1; off < 64; off <<= 1) {
        int t = __shfl_up(v, (unsigned)off, 64);
        if (lane >= off) v += t;
    }
    if (lane < nb) bsums[lane] = v - orig;   // exclusive
}

// pass 3: finalize rowptr, init cursor
__global__ void scan3(const int* __restrict__ deg, int* __restrict__ rowptr,
                      int* __restrict__ cursor, const int* __restrict__ bsums, int n) {
    int i = blockIdx.x * 256 + threadIdx.x;
    if (i >= n) return;
    int off = bsums[i >> 11];
    int incl = rowptr[1 + i] + off;
    rowptr[1 + i] = incl;
    cursor[i] = incl - deg[i];
    if (i == 0) rowptr[0] = 0;
}

__global__ void scatter_kernel(const int* __restrict__ srcw, const int* __restrict__ dstw,
                               int* __restrict__ cursor, int* __restrict__ col, int E) {
    int e = blockIdx.x * 256 + threadIdx.x;
    if (e < E) {
        int pos = atomicAdd(&cursor[dstw[e]], 1);
        col[pos] = srcw[e];
    }
}

// ---------------- GEMM1: h1[N,64] = x[N,512] @ W1[512,64] ----------------
__global__ __launch_bounds__(256) void gemm1(const float* __restrict__ x, const float* __restrict__ W,
                                             float* __restrict__ h1, int Nn) {
    __shared__ __align__(16) float xsT[32][68];   // [k][m]
    __shared__ __align__(16) float ws[32][64];    // [k][n]
    int tid = threadIdx.x;
    int m0 = blockIdx.x * 64;
    int tx = tid & 15, ty = tid >> 4;
    float acc[4][4] = {{0.f}};

    int lr = tid >> 2;            // 0..63 : row within tile
    int lk = (tid & 3) * 8;       // 0,8,16,24 : k offset
    int wrow = tid >> 3;          // 0..31
    int wcol = (tid & 7) * 8;     // 0..56
    bool rowok = (m0 + lr) < Nn;
    const float* xrow = x + (size_t)(m0 + lr) * F_IN;

    for (int k0 = 0; k0 < F_IN; k0 += 32) {
        float4 a0 = make_float4(0.f, 0.f, 0.f, 0.f), a1 = a0;
        if (rowok) {
            a0 = *(const float4*)(xrow + k0 + lk);
            a1 = *(const float4*)(xrow + k0 + lk + 4);
        }
        float4 b0 = *(const float4*)(W + (size_t)(k0 + wrow) * HC1 + wcol);
        float4 b1 = *(const float4*)(W + (size_t)(k0 + wrow) * HC1 + wcol + 4);
        __syncthreads();
        xsT[lk + 0][lr] = a0.x; xsT[lk + 1][lr] = a0.y;
        xsT[lk + 2][lr] = a0.z; xsT[lk + 3][lr] = a0.w;
        xsT[lk + 4][lr] = a1.x; xsT[lk + 5][lr] = a1.y;
        xsT[lk + 6][lr] = a1.z; xsT[lk + 7][lr] = a1.w;
        *(float4*)&ws[wrow][wcol] = b0;
        *(float4*)&ws[wrow][wcol + 4] = b1;
        __syncthreads();
#pragma unroll
        for (int kk = 0; kk < 32; ++kk) {
            float4 av = *(const float4*)&xsT[kk][ty * 4];
            float4 bv = *(const float4*)&ws[kk][tx * 4];
            float aa[4] = {av.x, av.y, av.z, av.w};
            float bb[4] = {bv.x, bv.y, bv.z, bv.w};
#pragma unroll
            for (int i = 0; i < 4; i++)
#pragma unroll
                for (int j = 0; j < 4; j++) acc[i][j] += aa[i] * bb[j];
        }
    }
#pragma unroll
    for (int i = 0; i < 4; i++) {
        int r = m0 + ty * 4 + i;
        if (r < Nn) {
            *(float4*)(h1 + (size_t)r * HC1 + tx * 4) =
                make_float4(acc[i][0], acc[i][1], acc[i][2], acc[i][3]);
        }
    }
}

// ---------------- alpha1: per-node per-head attention logits ----------------
__global__ void alpha1_kernel(const float* __restrict__ h1, const float* __restrict__ a_s,
                              const float* __restrict__ a_d, float* __restrict__ as1,
                              float* __restrict__ ad1, int Nn) {
    int idx = blockIdx.x * 256 + threadIdx.x;   // n*8 + h
    if (idx >= Nn * NH1) return;
    int h = idx & 7;
    const float* hp = h1 + (size_t)(idx >> 3) * HC1 + h * 8;
    float s = 0.f, d = 0.f;
#pragma unroll
    for (int c = 0; c < 8; c++) {
        float v = hp[c];
        s += v * a_s[h * 8 + c];
        d += v * a_d[h * 8 + c];
    }
    as1[idx] = s;
    ad1[idx] = d;
}

__device__ __forceinline__ float lrelu(float e) { return e > 0.f ? e : NEG_SLOPE * e; }

// ---------------- layer-1 aggregation ----------------
// one wave per dst node. Phase A: edge-parallel max over lanes. Phase B:
// edge-parallel sum of exp. Phase C: lane=channel weighted gather, unroll 4.
__global__ __launch_bounds__(256) void agg1(const float* __restrict__ h1, const float* __restrict__ as1,
                                            const float* __restrict__ ad1, const int* __restrict__ rowptr,
                                            const int* __restrict__ col, const float* __restrict__ b1,
                                            float* __restrict__ h2, int Nn) {
    int wave = (blockIdx.x * 256 + threadIdx.x) >> 6;
    int lane = threadIdx.x & 63;
    if (wave >= Nn) return;
    int d = wave;
    int jb = rowptr[d], je = rowptr[d + 1];
    const float4* as4 = (const float4*)as1;

    float ad[NH1], e0[NH1];
    {
        float4 s0 = as4[d * 2], s1 = as4[d * 2 + 1];
        float sv[8] = {s0.x, s0.y, s0.z, s0.w, s1.x, s1.y, s1.z, s1.w};
#pragma unroll
        for (int h = 0; h < NH1; h++) {
            ad[h] = ad1[d * NH1 + h];
            e0[h] = lrelu(sv[h] + ad[h]);
        }
    }
    // Phase A: max
    float m[NH1];
#pragma unroll
    for (int h = 0; h < NH1; h++) m[h] = e0[h];
    for (int j = jb + lane; j < je; j += 64) {
        int src = col[j];
        float4 a0 = as4[src * 2], a1 = as4[src * 2 + 1];
        float ev[8] = {a0.x, a0.y, a0.z, a0.w, a1.x, a1.y, a1.z, a1.w};
#pragma unroll
        for (int h = 0; h < NH1; h++) m[h] = fmaxf(m[h], lrelu(ev[h] + ad[h]));
    }
#pragma unroll
    for (int off = 32; off; off >>= 1)
#pragma unroll
        for (int h = 0; h < NH1; h++) m[h] = fmaxf(m[h], __shfl_xor(m[h], off, 64));
    // Phase B: sum of exp
    float s[NH1];
#pragma unroll
    for (int h = 0; h < NH1; h++) s[h] = (lane == 0) ? __expf(e0[h] - m[h]) : 0.f;
    for (int j = jb + lane; j < je; j += 64) {
        int src = col[j];
        float4 a0 = as4[src * 2], a1 = as4[src * 2 + 1];
        float ev[8] = {a0.x, a0.y, a0.z, a0.w, a1.x, a1.y, a1.z, a1.w};
#pragma unroll
        for (int h = 0; h < NH1; h++) s[h] += __expf(lrelu(ev[h] + ad[h]) - m[h]);
    }
#pragma unroll
    for (int off = 32; off; off >>= 1)
#pragma unroll
        for (int h = 0; h < NH1; h++) s[h] += __shfl_xor(s[h], off, 64);

    // Phase C: weighted gather, lane = channel (64 channels)
    int myh = lane >> 3;
    float mh = m[myh];
    float inv_s = 1.0f / (s[myh] + 1e-16f);
    float adv = ad[myh];
    float acc = __expf(e0[myh] - mh) * h1[(size_t)d * HC1 + lane];
    int j = jb;
    for (; j + 3 < je; j += 4) {
        int s0 = col[j], s1 = col[j + 1], s2 = col[j + 2], s3 = col[j + 3];
        float p0 = __expf(lrelu(as1[s0 * NH1 + myh] + adv) - mh);
        float p1 = __expf(lrelu(as1[s1 * NH1 + myh] + adv) - mh);
        float p2 = __expf(lrelu(as1[s2 * NH1 + myh] + adv) - mh);
        float p3 = __expf(lrelu(as1[s3 * NH1 + myh] + adv) - mh);
        float g0 = h1[(size_t)s0 * HC1 + lane];
        float g1 = h1[(size_t)s1 * HC1 + lane];
        float g2 = h1[(size_t)s2 * HC1 + lane];
        float g3 = h1[(size_t)s3 * HC1 + lane];
        acc += p0 * g0 + p1 * g1 + p2 * g2 + p3 * g3;
    }
    for (; j < je; j++) {
        int src = col[j];
        float p = __expf(lrelu(as1[src * NH1 + myh] + adv) - mh);
        acc += p * h1[(size_t)src * HC1 + lane];
    }
    float o = acc * inv_s + b1[lane];
    o = o > 0.f ? o : __expf(o) - 1.0f;     // ELU
    h2[(size_t)d * HC1 + lane] = o;
}

// ---------------- GEMM2 + alpha2 ----------------
__global__ __launch_bounds__(256) void gemm2(const float* __restrict__ h2, const float* __restrict__ W2,
                                             const float* __restrict__ av_in, const float* __restrict__ dv_in,
                                             float* __restrict__ g, float* __restrict__ as2,
                                             float* __restrict__ ad2, int Nn) {
    __shared__ float W2s[HC1 * NC];
    __shared__ float hrow[4][HC1];
    __shared__ float avec[NC], dvec[NC];
    int tid = threadIdx.x;
    for (int i = tid; i < HC1 * NC; i += 256) W2s[i] = W2[i];
    if (tid < NC) { avec[tid] = av_in[tid]; dvec[tid] = dv_in[tid]; }
    int w = tid >> 6, lane = tid & 63;
    int n = blockIdx.x * 4 + w;
    float hv = 0.f;
    if (n < Nn) hv = h2[(size_t)n * HC1 + lane];
    hrow[w][lane] = hv;
    __syncthreads();
    float acc = 0.f;
    bool act = (n < Nn) && (lane < NC);
    if (act) {
#pragma unroll
        for (int k = 0; k < HC1; k++) acc += hrow[w][k] * W2s[k * NC + lane];
        g[(size_t)n * NC + lane] = acc;
    }
    float va = act ? acc * avec[lane] : 0.f;
    float vd = act ? acc * dvec[lane] : 0.f;
    for (int off = 32; off; off >>= 1) {
        va += __shfl_xor(va, off, 64);
        vd += __shfl_xor(vd, off, 64);
    }
    if (n < Nn && lane == 0) { as2[n] = va; ad2[n] = vd; }
}

// ---------------- layer-2 aggregation + bias + log_softmax ----------------
__global__ __launch_bounds__(256) void agg2(const float* __restrict__ g, const float* __restrict__ as2,
                                            const float* __restrict__ ad2, const int* __restrict__ rowptr,
                                            const int* __restrict__ col, const float* __restrict__ b2,
                                            float* __restrict__ out, int Nn) {
    int wave = (blockIdx.x * 256 + threadIdx.x) >> 6;
    int lane = threadIdx.x & 63;
    if (wave >= Nn) return;
    int d = wave;
    int jb = rowptr[d], je = rowptr[d + 1];
    float adv = ad2[d];
    float e0 = lrelu(as2[d] + adv);
    // Phase A: max (edge-parallel)
    float m = e0;
    for (int j = jb + lane; j < je; j += 64) m = fmaxf(m, lrelu(as2[col[j]] + adv));
#pragma unroll
    for (int off = 32; off; off >>= 1) m = fmaxf(m, __shfl_xor(m, off, 64));
    // Phase B: sum of exp (edge-parallel)
    float s = (lane == 0) ? __expf(e0 - m) : 0.f;
    for (int j = jb + lane; j < je; j += 64) s += __expf(lrelu(as2[col[j]] + adv) - m);
#pragma unroll
    for (int off = 32; off; off >>= 1) s += __shfl_xor(s, off, 64);
    float inv_s = 1.0f / (s + 1e-16f);

    // Phase C: weighted gather (lanes 0..39 = classes), unroll 4
    float acc = (lane < NC) ? __expf(e0 - m) * g[(size_t)d * NC + lane] : 0.f;
    int j = jb;
    for (; j + 3 < je; j += 4) {
        int s0 = col[j], s1 = col[j + 1], s2 = col[j + 2], s3 = col[j + 3];
        float p0 = __expf(lrelu(as2[s0] + adv) - m);
        float p1 = __expf(lrelu(as2[s1] + adv) - m);
        float p2 = __expf(lrelu(as2[s2] + adv) - m);
        float p3 = __expf(lrelu(as2[s3] + adv) - m);
        if (lane < NC) {
            float g0 = g[(size_t)s0 * NC + lane];
            float g1 = g[(size_t)s1 * NC + lane];
            float g2 = g[(size_t)s2 * NC + lane];
            float g3 = g[(size_t)s3 * NC + lane];
            acc += p0 * g0 + p1 * g1 + p2 * g2 + p3 * g3;
        }
    }
    for (; j < je; j++) {
        int src = col[j];
        float p = __expf(lrelu(as2[src] + adv) - m);
        if (lane < NC) acc += p * g[(size_t)src * NC + lane];
    }
    float o = acc * inv_s + ((lane < NC) ? b2[lane] : 0.f);
    // log_softmax over lanes 0..39
    float vm = (lane < NC) ? o : -1e30f;
#pragma unroll
    for (int off = 32; off; off >>= 1) vm = fmaxf(vm, __shfl_xor(vm, off, 64));
    float ex = (lane < NC) ? __expf(o - vm) : 0.f;
#pragma unroll
    for (int off = 32; off; off >>= 1) ex += __shfl_xor(ex, off, 64);
    float lsm = o - vm - __logf(ex);
    if (lane < NC) out[(size_t)d * NC + lane] = lsm;
}

// ---------------- host launch ----------------
extern "C" void kernel_launch(void* const* d_in, const int* in_sizes, int n_in,
                              void* d_out, int out_size, void* d_ws, size_t ws_size,
                              hipStream_t stream) {
    const float* x      = (const float*)d_in[0];
    const int*   ei     = (const int*)d_in[1];
    const float* W1     = (const float*)d_in[2];
    const float* a_src1 = (const float*)d_in[3];
    const float* a_dst1 = (const float*)d_in[4];
    const float* b1     = (const float*)d_in[5];
    const float* W2     = (const float*)d_in[6];
    const float* a_src2 = (const float*)d_in[7];
    const float* a_dst2 = (const float*)d_in[8];
    const float* b2     = (const float*)d_in[9];
    float* out = (float*)d_out;

    const int N = in_sizes[0] / F_IN;       // 100000
    const int E = in_sizes[1] / 2;          // 1600000

    char* p = (char*)d_ws;
    auto alloc = [&](size_t bytes) -> void* {
        void* r = (void*)p;
        p += (bytes + 255) & ~(size_t)255;
        return r;
    };
    int* srcw   = (int*)alloc((size_t)E * 4);
    int* dstw   = (int*)alloc((size_t)E * 4);
    int* deg    = (int*)alloc((size_t)N * 4);
    int* rowptr = (int*)alloc(((size_t)N + 1) * 4);
    int* cursor = (int*)alloc((size_t)N * 4);
    int* bsums  = (int*)alloc(64 * 4);
    int* flag   = (int*)alloc(256);
    int* col    = (int*)alloc((size_t)E * 4);
    float* h1   = (float*)alloc((size_t)N * HC1 * 4);   // reused as g
    float* as1  = (float*)alloc((size_t)N * NH1 * 4);   // reused as as2
    float* ad1  = (float*)alloc((size_t)N * NH1 * 4);   // reused as ad2
    float* h2   = (float*)alloc((size_t)N * HC1 * 4);
    float* g    = h1;
    float* as2  = as1;
    float* ad2  = ad1;

    // --- edge normalization + CSR build ---
    hipMemsetAsync(deg, 0, (size_t)N * 4, stream);
    detect_i64<<<1, 256, 0, stream>>>(ei, flag, 4096);
    int ge = (E + 255) / 256;
    normalize_edges<<<ge, 256, 0, stream>>>(ei, flag, srcw, dstw, deg, E);
    int nb = (N + SCAN_CHUNK - 1) / SCAN_CHUNK;     // 49, fits in one wave
    scan1<<<nb, 256, 0, stream>>>(deg, rowptr, bsums, N);
    scan2<<<1, 64, 0, stream>>>(bsums, nb);
    scan3<<<(N + 255) / 256, 256, 0, stream>>>(deg, rowptr, cursor, bsums, N);
    scatter_kernel<<<ge, 256, 0, stream>>>(srcw, dstw, cursor, col, E);

    // --- layer 1 ---
    gemm1<<<(N + 63) / 64, 256, 0, stream>>>(x, W1, h1, N);
    alpha1_kernel<<<(N * NH1 + 255) / 256, 256, 0, stream>>>(h1, a_src1, a_dst1, as1, ad1, N);
    agg1<<<(N + 3) / 4, 256, 0, stream>>>(h1, as1, ad1, rowptr, col, b1, h2, N);

    // --- layer 2 ---
    gemm2<<<(N + 3) / 4, 256, 0, stream>>>(h2, W2, a_src2, a_dst2, g, as2, ad2, N);
    agg2<<<(N + 3) / 4, 256, 0, stream>>>(g, as2, ad2, rowptr, col, b2, out, N);
}

// Round 3
// 753.368 us; speedup vs baseline: 1.2807x; 1.1301x over previous
//
#include <hip/hip_runtime.h>
#include <hip/hip_bf16.h>

// ---------------- problem constants (from reference) ----------------
// N = 100000 nodes, E = 1600000 edges, F_IN = 512, H1*C1 = 64, NUM_CLASSES = 40
#define F_IN 512
#define HC1 64          // 8 heads * 8 ch
#define NH1 8
#define NC 40
#define NEG_SLOPE 0.2f
#define SCAN_CHUNK 2048

// ---------------- edge-index normalization ----------------
__global__ void detect_i64(const int* __restrict__ ei, int* __restrict__ flag, int n_check) {
    __shared__ int found;
    if (threadIdx.x == 0) found = 0;
    __syncthreads();
    for (int i = threadIdx.x; i < n_check; i += 256) {
        if (ei[2 * i + 1] != 0) atomicOr(&found, 1);
    }
    __syncthreads();
    if (threadIdx.x == 0) *flag = (found == 0) ? 1 : 0;   // 1 => int64
}

// normalize + degree histogram fused
__global__ void normalize_edges(const int* __restrict__ ei, const int* __restrict__ flag,
                                int* __restrict__ srcw, int* __restrict__ dstw,
                                int* __restrict__ deg, int E) {
    int e = blockIdx.x * 256 + threadIdx.x;
    if (e >= E) return;
    int f = *flag;
    int s, d;
    if (f) { s = ei[2 * e]; d = ei[2 * (E + e)]; }
    else   { s = ei[e];     d = ei[E + e]; }
    srcw[e] = s;
    dstw[e] = d;
    atomicAdd(&deg[d], 1);
}

// ---------------- CSR build ----------------
__global__ __launch_bounds__(256) void scan1(const int* __restrict__ deg, int* __restrict__ rowptr,
                                             int* __restrict__ bsums, int n) {
    __shared__ int sbuf[256];
    int tid = threadIdx.x;
    int base = blockIdx.x * SCAN_CHUNK + tid * 8;
    int v[8];
#pragma unroll
    for (int j = 0; j < 8; j++) { int idx = base + j; v[j] = (idx < n) ? deg[idx] : 0; }
    int tsum = 0;
#pragma unroll
    for (int j = 0; j < 8; j++) tsum += v[j];
    sbuf[tid] = tsum;
    __syncthreads();
    for (int off = 1; off < 256; off <<= 1) {
        int t = (tid >= off) ? sbuf[tid - off] : 0;
        __syncthreads();
        sbuf[tid] += t;
        __syncthreads();
    }
    int run = sbuf[tid] - tsum;
#pragma unroll
    for (int j = 0; j < 8; j++) {
        run += v[j];
        int idx = base + j;
        if (idx < n) rowptr[1 + idx] = run;
    }
    if (tid == 255) bsums[blockIdx.x] = sbuf[255];
}

__global__ void scan2(int* __restrict__ bsums, int nb) {
    int lane = threadIdx.x & 63;
    int v = (lane < nb) ? bsums[lane] : 0;
    int orig = v;
    for (int off = 1; off < 64; off <<= 1) {
        int t = __shfl_up(v, (unsigned)off, 64);
        if (lane >= off) v += t;
    }
    if (lane < nb) bsums[lane] = v - orig;
}

__global__ void scan3(const int* __restrict__ deg, int* __restrict__ rowptr,
                      int* __restrict__ cursor, const int* __restrict__ bsums, int n) {
    int i = blockIdx.x * 256 + threadIdx.x;
    if (i >= n) return;
    int off = bsums[i >> 11];
    int incl = rowptr[1 + i] + off;
    rowptr[1 + i] = incl;
    cursor[i] = incl - deg[i];
    if (i == 0) rowptr[0] = 0;
}

__global__ void scatter_kernel(const int* __restrict__ srcw, const int* __restrict__ dstw,
                               int* __restrict__ cursor, int* __restrict__ col, int E) {
    int e = blockIdx.x * 256 + threadIdx.x;
    if (e < E) {
        int pos = atomicAdd(&cursor[dstw[e]], 1);
        col[pos] = srcw[e];
    }
}

// ---------------- GEMM1: h1[N,64] = x[N,512] @ W1[512,64] ----------------
__global__ __launch_bounds__(256) void gemm1(const float* __restrict__ x, const float* __restrict__ W,
                                             float* __restrict__ h1, int Nn) {
    __shared__ __align__(16) float xsT[32][68];
    __shared__ __align__(16) float ws[32][64];
    int tid = threadIdx.x;
    int m0 = blockIdx.x * 64;
    int tx = tid & 15, ty = tid >> 4;
    float acc[4][4] = {{0.f}};

    int lr = tid >> 2;
    int lk = (tid & 3) * 8;
    int wrow = tid >> 3;
    int wcol = (tid & 7) * 8;
    bool rowok = (m0 + lr) < Nn;
    const float* xrow = x + (size_t)(m0 + lr) * F_IN;

    for (int k0 = 0; k0 < F_IN; k0 += 32) {
        float4 a0 = make_float4(0.f, 0.f, 0.f, 0.f), a1 = a0;
        if (rowok) {
            a0 = *(const float4*)(xrow + k0 + lk);
            a1 = *(const float4*)(xrow + k0 + lk + 4);
        }
        float4 b0 = *(const float4*)(W + (size_t)(k0 + wrow) * HC1 + wcol);
        float4 b1 = *(const float4*)(W + (size_t)(k0 + wrow) * HC1 + wcol + 4);
        __syncthreads();
        xsT[lk + 0][lr] = a0.x; xsT[lk + 1][lr] = a0.y;
        xsT[lk + 2][lr] = a0.z; xsT[lk + 3][lr] = a0.w;
        xsT[lk + 4][lr] = a1.x; xsT[lk + 5][lr] = a1.y;
        xsT[lk + 6][lr] = a1.z; xsT[lk + 7][lr] = a1.w;
        *(float4*)&ws[wrow][wcol] = b0;
        *(float4*)&ws[wrow][wcol + 4] = b1;
        __syncthreads();
#pragma unroll
        for (int kk = 0; kk < 32; ++kk) {
            float4 av = *(const float4*)&xsT[kk][ty * 4];
            float4 bv = *(const float4*)&ws[kk][tx * 4];
            float aa[4] = {av.x, av.y, av.z, av.w};
            float bb[4] = {bv.x, bv.y, bv.z, bv.w};
#pragma unroll
            for (int i = 0; i < 4; i++)
#pragma unroll
                for (int j = 0; j < 4; j++) acc[i][j] += aa[i] * bb[j];
        }
    }
#pragma unroll
    for (int i = 0; i < 4; i++) {
        int r = m0 + ty * 4 + i;
        if (r < Nn) {
            *(float4*)(h1 + (size_t)r * HC1 + tx * 4) =
                make_float4(acc[i][0], acc[i][1], acc[i][2], acc[i][3]);
        }
    }
}

// ---------------- alpha1 ----------------
__global__ void alpha1_kernel(const float* __restrict__ h1, const float* __restrict__ a_s,
                              const float* __restrict__ a_d, float* __restrict__ as1,
                              float* __restrict__ ad1, int Nn) {
    int idx = blockIdx.x * 256 + threadIdx.x;   // n*8 + h
    if (idx >= Nn * NH1) return;
    int h = idx & 7;
    const float* hp = h1 + (size_t)(idx >> 3) * HC1 + h * 8;
    float s = 0.f, d = 0.f;
#pragma unroll
    for (int c = 0; c < 8; c++) {
        float v = hp[c];
        s += v * a_s[h * 8 + c];
        d += v * a_d[h * 8 + c];
    }
    as1[idx] = s;
    ad1[idx] = d;
}

__device__ __forceinline__ float lrelu(float e) { return e > 0.f ? e : NEG_SLOPE * e; }

// ---------------- layer-1 aggregation ----------------
// One wave per dst node. Softmax anchored at the self-loop logit e0[h]
// (mathematically identical to max-subtraction; |e-e0| <~ 12 so exp is safe).
// Per 64-edge chunk: lane=edge computes the 8 head weights ONCE -> LDS;
// gather loop reads p via LDS broadcast and accumulates BOTH numerator and
// denominator (no cross-lane reductions at all).
__global__ __launch_bounds__(256) void agg1(const float* __restrict__ h1, const float* __restrict__ as1,
                                            const float* __restrict__ ad1, const int* __restrict__ rowptr,
                                            const int* __restrict__ col, const float* __restrict__ b1,
                                            float* __restrict__ h2, int Nn) {
    __shared__ float pbuf[4][NH1 * 68];   // stride 68: conflict-free stores + 8-bank broadcast reads
    int w = threadIdx.x >> 6;
    int wave = (blockIdx.x * 256 + threadIdx.x) >> 6;
    int lane = threadIdx.x & 63;
    if (wave >= Nn) return;
    int d = wave;
    int jb = rowptr[d], je = rowptr[d + 1];
    const float4* as4 = (const float4*)as1;
    const float4* ad4 = (const float4*)ad1;

    float4 sd0 = as4[d * 2], sd1 = as4[d * 2 + 1];
    float4 dd0 = ad4[d * 2], dd1 = ad4[d * 2 + 1];
    float ad[8] = {dd0.x, dd0.y, dd0.z, dd0.w, dd1.x, dd1.y, dd1.z, dd1.w};
    float sv[8] = {sd0.x, sd0.y, sd0.z, sd0.w, sd1.x, sd1.y, sd1.z, sd1.w};
    float e0[8];
#pragma unroll
    for (int h = 0; h < NH1; h++) e0[h] = lrelu(sv[h] + ad[h]);

    int myh = lane >> 3;
    float acc = h1[(size_t)d * HC1 + lane];    // self-loop, p = exp(0) = 1
    float ssum = 1.0f;
    float* pb = pbuf[w];

    for (int c0 = jb; c0 < je; c0 += 64) {
        int nc = min(64, je - c0);
        int srcv = d;
        if (lane < nc) srcv = col[c0 + lane];
        float4 a0 = as4[srcv * 2], a1 = as4[srcv * 2 + 1];
        float ev[8] = {a0.x, a0.y, a0.z, a0.w, a1.x, a1.y, a1.z, a1.w};
#pragma unroll
        for (int h = 0; h < NH1; h++)
            pb[h * 68 + lane] = __expf(lrelu(ev[h] + ad[h]) - e0[h]);

        int jj = 0;
        for (; jj + 3 < nc; jj += 4) {
            int s0 = __shfl(srcv, jj, 64), s1 = __shfl(srcv, jj + 1, 64);
            int s2 = __shfl(srcv, jj + 2, 64), s3 = __shfl(srcv, jj + 3, 64);
            float p0 = pb[myh * 68 + jj],     p1 = pb[myh * 68 + jj + 1];
            float p2 = pb[myh * 68 + jj + 2], p3 = pb[myh * 68 + jj + 3];
            float g0 = h1[(size_t)s0 * HC1 + lane];
            float g1 = h1[(size_t)s1 * HC1 + lane];
            float g2 = h1[(size_t)s2 * HC1 + lane];
            float g3 = h1[(size_t)s3 * HC1 + lane];
            ssum += (p0 + p1) + (p2 + p3);
            acc += p0 * g0 + p1 * g1 + p2 * g2 + p3 * g3;
        }
        for (; jj < nc; jj++) {
            int s0 = __shfl(srcv, jj, 64);
            float p0 = pb[myh * 68 + jj];
            ssum += p0;
            acc += p0 * h1[(size_t)s0 * HC1 + lane];
        }
    }
    float o = acc / (ssum + 1e-16f) + b1[lane];
    o = o > 0.f ? o : __expf(o) - 1.0f;     // ELU
    h2[(size_t)d * HC1 + lane] = o;
}

// ---------------- GEMM2 + alpha2 ----------------
__global__ __launch_bounds__(256) void gemm2(const float* __restrict__ h2, const float* __restrict__ W2,
                                             const float* __restrict__ av_in, const float* __restrict__ dv_in,
                                             float* __restrict__ g, float* __restrict__ as2,
                                             float* __restrict__ ad2, int Nn) {
    __shared__ float W2s[HC1 * NC];
    __shared__ float hrow[4][HC1];
    __shared__ float avec[NC], dvec[NC];
    int tid = threadIdx.x;
    for (int i = tid; i < HC1 * NC; i += 256) W2s[i] = W2[i];
    if (tid < NC) { avec[tid] = av_in[tid]; dvec[tid] = dv_in[tid]; }
    int w = tid >> 6, lane = tid & 63;
    int n = blockIdx.x * 4 + w;
    float hv = 0.f;
    if (n < Nn) hv = h2[(size_t)n * HC1 + lane];
    hrow[w][lane] = hv;
    __syncthreads();
    float acc = 0.f;
    bool act = (n < Nn) && (lane < NC);
    if (act) {
#pragma unroll
        for (int k = 0; k < HC1; k++) acc += hrow[w][k] * W2s[k * NC + lane];
        g[(size_t)n * NC + lane] = acc;
    }
    float va = act ? acc * avec[lane] : 0.f;
    float vd = act ? acc * dvec[lane] : 0.f;
    for (int off = 32; off; off >>= 1) {
        va += __shfl_xor(va, off, 64);
        vd += __shfl_xor(vd, off, 64);
    }
    if (n < Nn && lane == 0) { as2[n] = va; ad2[n] = vd; }
}

// ---------------- layer-2 aggregation + bias + log_softmax ----------------
__global__ __launch_bounds__(256) void agg2(const float* __restrict__ g, const float* __restrict__ as2,
                                            const float* __restrict__ ad2, const int* __restrict__ rowptr,
                                            const int* __restrict__ col, const float* __restrict__ b2,
                                            float* __restrict__ out, int Nn) {
    __shared__ float pbuf[4][64];
    int w = threadIdx.x >> 6;
    int wave = (blockIdx.x * 256 + threadIdx.x) >> 6;
    int lane = threadIdx.x & 63;
    if (wave >= Nn) return;
    int d = wave;
    int jb = rowptr[d], je = rowptr[d + 1];
    float adv = ad2[d];
    float e0 = lrelu(as2[d] + adv);
    float acc = (lane < NC) ? g[(size_t)d * NC + lane] : 0.f;   // self-loop p = 1
    float ssum = 1.0f;
    float* pb = pbuf[w];

    for (int c0 = jb; c0 < je; c0 += 64) {
        int nc = min(64, je - c0);
        int srcv = d;
        if (lane < nc) srcv = col[c0 + lane];
        pb[lane] = __expf(lrelu(as2[srcv] + adv) - e0);

        int jj = 0;
        for (; jj + 3 < nc; jj += 4) {
            int s0 = __shfl(srcv, jj, 64), s1 = __shfl(srcv, jj + 1, 64);
            int s2 = __shfl(srcv, jj + 2, 64), s3 = __shfl(srcv, jj + 3, 64);
            float p0 = pb[jj], p1 = pb[jj + 1], p2 = pb[jj + 2], p3 = pb[jj + 3];
            float g0 = 0.f, g1 = 0.f, g2 = 0.f, g3 = 0.f;
            if (lane < NC) {
                g0 = g[(size_t)s0 * NC + lane];
                g1 = g[(size_t)s1 * NC + lane];
                g2 = g[(size_t)s2 * NC + lane];
                g3 = g[(size_t)s3 * NC + lane];
            }
            ssum += (p0 + p1) + (p2 + p3);
            acc += p0 * g0 + p1 * g1 + p2 * g2 + p3 * g3;
        }
        for (; jj < nc; jj++) {
            int s0 = __shfl(srcv, jj, 64);
            float p0 = pb[jj];
            ssum += p0;
            if (lane < NC) acc += p0 * g[(size_t)s0 * NC + lane];
        }
    }
    float o = acc / (ssum + 1e-16f) + ((lane < NC) ? b2[lane] : 0.f);
    // log_softmax over lanes 0..39
    float vm = (lane < NC) ? o : -1e30f;
#pragma unroll
    for (int off = 32; off; off >>= 1) vm = fmaxf(vm, __shfl_xor(vm, off, 64));
    float ex = (lane < NC) ? __expf(o - vm) : 0.f;
#pragma unroll
    for (int off = 32; off; off >>= 1) ex += __shfl_xor(ex, off, 64);
    float lsm = o - vm - __logf(ex);
    if (lane < NC) out[(size_t)d * NC + lane] = lsm;
}

// ---------------- host launch ----------------
extern "C" void kernel_launch(void* const* d_in, const int* in_sizes, int n_in,
                              void* d_out, int out_size, void* d_ws, size_t ws_size,
                              hipStream_t stream) {
    const float* x      = (const float*)d_in[0];
    const int*   ei     = (const int*)d_in[1];
    const float* W1     = (const float*)d_in[2];
    const float* a_src1 = (const float*)d_in[3];
    const float* a_dst1 = (const float*)d_in[4];
    const float* b1     = (const float*)d_in[5];
    const float* W2     = (const float*)d_in[6];
    const float* a_src2 = (const float*)d_in[7];
    const float* a_dst2 = (const float*)d_in[8];
    const float* b2     = (const float*)d_in[9];
    float* out = (float*)d_out;

    const int N = in_sizes[0] / F_IN;       // 100000
    const int E = in_sizes[1] / 2;          // 1600000

    char* p = (char*)d_ws;
    auto alloc = [&](size_t bytes) -> void* {
        void* r = (void*)p;
        p += (bytes + 255) & ~(size_t)255;
        return r;
    };
    int* srcw   = (int*)alloc((size_t)E * 4);
    int* dstw   = (int*)alloc((size_t)E * 4);
    int* deg    = (int*)alloc((size_t)N * 4);
    int* rowptr = (int*)alloc(((size_t)N + 1) * 4);
    int* cursor = (int*)alloc((size_t)N * 4);
    int* bsums  = (int*)alloc(64 * 4);
    int* flag   = (int*)alloc(256);
    int* col    = (int*)alloc((size_t)E * 4);
    float* h1   = (float*)alloc((size_t)N * HC1 * 4);   // reused as g
    float* as1  = (float*)alloc((size_t)N * NH1 * 4);   // reused as as2
    float* ad1  = (float*)alloc((size_t)N * NH1 * 4);   // reused as ad2
    float* h2   = (float*)alloc((size_t)N * HC1 * 4);
    float* g    = h1;
    float* as2  = as1;
    float* ad2  = ad1;

    // --- edge normalization + CSR build ---
    hipMemsetAsync(deg, 0, (size_t)N * 4, stream);
    detect_i64<<<1, 256, 0, stream>>>(ei, flag, 4096);
    int ge = (E + 255) / 256;
    normalize_edges<<<ge, 256, 0, stream>>>(ei, flag, srcw, dstw, deg, E);
    int nb = (N + SCAN_CHUNK - 1) / SCAN_CHUNK;
    scan1<<<nb, 256, 0, stream>>>(deg, rowptr, bsums, N);
    scan2<<<1, 64, 0, stream>>>(bsums, nb);
    scan3<<<(N + 255) / 256, 256, 0, stream>>>(deg, rowptr, cursor, bsums, N);
    scatter_kernel<<<ge, 256, 0, stream>>>(srcw, dstw, cursor, col, E);

    // --- layer 1 ---
    gemm1<<<(N + 63) / 64, 256, 0, stream>>>(x, W1, h1, N);
    alpha1_kernel<<<(N * NH1 + 255) / 256, 256, 0, stream>>>(h1, a_src1, a_dst1, as1, ad1, N);
    agg1<<<(N + 3) / 4, 256, 0, stream>>>(h1, as1, ad1, rowptr, col, b1, h2, N);

    // --- layer 2 ---
    gemm2<<<(N + 3) / 4, 256, 0, stream>>>(h2, W2, a_src2, a_dst2, g, as2, ad2, N);
    agg2<<<(N + 3) / 4, 256, 0, stream>>>(g, as2, ad2, rowptr, col, b2, out, N);
}

// Round 4
// 669.411 us; speedup vs baseline: 1.4413x; 1.1254x over previous
//
#include <hip/hip_runtime.h>
#include <hip/hip_bf16.h>

// ---------------- problem constants (from reference) ----------------
// N = 100000 nodes, E = 1600000 edges, F_IN = 512, H1*C1 = 64, NUM_CLASSES = 40
#define F_IN 512
#define HC1 64          // 8 heads * 8 ch
#define NH1 8
#define NC 40
#define NEG_SLOPE 0.2f
#define SCAN_CHUNK 2048
#define RADIX_EPB 4096  // edges per block in scatter1
#define MAXNB 512       // max node buckets (256 nodes each) supported

// ---------------- edge-index dtype detection ----------------
__global__ void detect_i64(const int* __restrict__ ei, int* __restrict__ flag, int n_check) {
    __shared__ int found;
    if (threadIdx.x == 0) found = 0;
    __syncthreads();
    for (int i = threadIdx.x; i < n_check; i += 256) {
        if (ei[2 * i + 1] != 0) atomicOr(&found, 1);
    }
    __syncthreads();
    if (threadIdx.x == 0) *flag = (found == 0) ? 1 : 0;   // 1 => int64
}

// degree histogram: reads only the dst half of edge_index
__global__ void hist_kernel(const int* __restrict__ ei, const int* __restrict__ flag,
                            int* __restrict__ deg, int E) {
    int e = blockIdx.x * 256 + threadIdx.x;
    if (e >= E) return;
    int f = *flag;
    int d = f ? ei[2 * (E + e)] : ei[E + e];
    atomicAdd(&deg[d], 1);
}

// ---------------- CSR build: scans ----------------
__global__ __launch_bounds__(256) void scan1(const int* __restrict__ deg, int* __restrict__ rowptr,
                                             int* __restrict__ bsums, int n) {
    __shared__ int sbuf[256];
    int tid = threadIdx.x;
    int base = blockIdx.x * SCAN_CHUNK + tid * 8;
    int v[8];
#pragma unroll
    for (int j = 0; j < 8; j++) { int idx = base + j; v[j] = (idx < n) ? deg[idx] : 0; }
    int tsum = 0;
#pragma unroll
    for (int j = 0; j < 8; j++) tsum += v[j];
    sbuf[tid] = tsum;
    __syncthreads();
    for (int off = 1; off < 256; off <<= 1) {
        int t = (tid >= off) ? sbuf[tid - off] : 0;
        __syncthreads();
        sbuf[tid] += t;
        __syncthreads();
    }
    int run = sbuf[tid] - tsum;
#pragma unroll
    for (int j = 0; j < 8; j++) {
        run += v[j];
        int idx = base + j;
        if (idx < n) rowptr[1 + idx] = run;
    }
    if (tid == 255) bsums[blockIdx.x] = sbuf[255];
}

__global__ void scan2(int* __restrict__ bsums, int nb) {
    int lane = threadIdx.x & 63;
    int v = (lane < nb) ? bsums[lane] : 0;
    int orig = v;
    for (int off = 1; off < 64; off <<= 1) {
        int t = __shfl_up(v, (unsigned)off, 64);
        if (lane >= off) v += t;
    }
    if (lane < nb) bsums[lane] = v - orig;
}

// finalize rowptr; init bucket append cursors (bucket b starts at rowptr[b*256])
__global__ void scan3(const int* __restrict__ deg, int* __restrict__ rowptr,
                      int* __restrict__ bcur, const int* __restrict__ bsums, int n) {
    int i = blockIdx.x * 256 + threadIdx.x;
    if (i >= n) return;
    int off = bsums[i >> 11];
    int incl = rowptr[1 + i] + off;
    rowptr[1 + i] = incl;
    if ((i & 255) == 0) bcur[i >> 8] = incl - deg[i];
    if (i == 0) rowptr[0] = 0;
}

// ---------------- scatter pass 1: block-binned append into 256-node buckets --------
__global__ __launch_bounds__(256) void scatter1(const int* __restrict__ ei, const int* __restrict__ flag,
                                                int* __restrict__ bcur, int2* __restrict__ pairs,
                                                int E, int NB) {
    __shared__ int cnt[MAXNB];
    __shared__ int gb[MAXNB];
    int tid = threadIdx.x;
    for (int i = tid; i < NB; i += 256) cnt[i] = 0;
    __syncthreads();
    int f = *flag;
    int base = blockIdx.x * RADIX_EPB;
    int sv[16], dv[16], rv[16];
#pragma unroll
    for (int i = 0; i < 16; i++) {
        int e = base + i * 256 + tid;
        if (e < E) {
            int s, d;
            if (f) { s = ei[2 * e]; d = ei[2 * (E + e)]; }
            else   { s = ei[e];     d = ei[E + e]; }
            sv[i] = s; dv[i] = d;
            rv[i] = atomicAdd(&cnt[d >> 8], 1);
        }
    }
    __syncthreads();
    for (int i = tid; i < NB; i += 256) {
        int c = cnt[i];
        gb[i] = c ? atomicAdd(&bcur[i], c) : 0;
    }
    __syncthreads();
#pragma unroll
    for (int i = 0; i < 16; i++) {
        int e = base + i * 256 + tid;
        if (e < E) {
            int pos = gb[dv[i] >> 8] + rv[i];
            pairs[pos] = make_int2(sv[i], dv[i]);
        }
    }
}

// ---------------- scatter pass 2: per-bucket finalize (LDS cursors) ----------------
__global__ __launch_bounds__(256) void scatter2(const int2* __restrict__ pairs,
                                                const int* __restrict__ rowptr,
                                                int* __restrict__ col, int Nn) {
    __shared__ int cur[256];
    int b = blockIdx.x;
    int node0 = b << 8;
    int tid = threadIdx.x;
    int nlast = min(node0 + 256, Nn);
    if (node0 + tid < nlast) cur[tid] = rowptr[node0 + tid];
    __syncthreads();
    int jb = rowptr[node0];
    int je = rowptr[nlast];
    for (int j = jb + tid; j < je; j += 256) {
        int2 pr = pairs[j];
        int pos = atomicAdd(&cur[pr.y - node0], 1);
        col[pos] = pr.x;
    }
}

// ---------------- GEMM1: h1[N,64] = x[N,512] @ W1[512,64] ----------------
__global__ __launch_bounds__(256) void gemm1(const float* __restrict__ x, const float* __restrict__ W,
                                             float* __restrict__ h1, int Nn) {
    __shared__ __align__(16) float xsT[32][68];
    __shared__ __align__(16) float ws[32][64];
    int tid = threadIdx.x;
    int m0 = blockIdx.x * 64;
    int tx = tid & 15, ty = tid >> 4;
    float acc[4][4] = {{0.f}};

    int lr = tid >> 2;
    int lk = (tid & 3) * 8;
    int wrow = tid >> 3;
    int wcol = (tid & 7) * 8;
    bool rowok = (m0 + lr) < Nn;
    const float* xrow = x + (size_t)(m0 + lr) * F_IN;

    for (int k0 = 0; k0 < F_IN; k0 += 32) {
        float4 a0 = make_float4(0.f, 0.f, 0.f, 0.f), a1 = a0;
        if (rowok) {
            a0 = *(const float4*)(xrow + k0 + lk);
            a1 = *(const float4*)(xrow + k0 + lk + 4);
        }
        float4 b0 = *(const float4*)(W + (size_t)(k0 + wrow) * HC1 + wcol);
        float4 b1 = *(const float4*)(W + (size_t)(k0 + wrow) * HC1 + wcol + 4);
        __syncthreads();
        xsT[lk + 0][lr] = a0.x; xsT[lk + 1][lr] = a0.y;
        xsT[lk + 2][lr] = a0.z; xsT[lk + 3][lr] = a0.w;
        xsT[lk + 4][lr] = a1.x; xsT[lk + 5][lr] = a1.y;
        xsT[lk + 6][lr] = a1.z; xsT[lk + 7][lr] = a1.w;
        *(float4*)&ws[wrow][wcol] = b0;
        *(float4*)&ws[wrow][wcol + 4] = b1;
        __syncthreads();
#pragma unroll
        for (int kk = 0; kk < 32; ++kk) {
            float4 av = *(const float4*)&xsT[kk][ty * 4];
            float4 bv = *(const float4*)&ws[kk][tx * 4];
            float aa[4] = {av.x, av.y, av.z, av.w};
            float bb[4] = {bv.x, bv.y, bv.z, bv.w};
#pragma unroll
            for (int i = 0; i < 4; i++)
#pragma unroll
                for (int j = 0; j < 4; j++) acc[i][j] += aa[i] * bb[j];
        }
    }
#pragma unroll
    for (int i = 0; i < 4; i++) {
        int r = m0 + ty * 4 + i;
        if (r < Nn) {
            *(float4*)(h1 + (size_t)r * HC1 + tx * 4) =
                make_float4(acc[i][0], acc[i][1], acc[i][2], acc[i][3]);
        }
    }
}

// ---------------- alpha1 ----------------
__global__ void alpha1_kernel(const float* __restrict__ h1, const float* __restrict__ a_s,
                              const float* __restrict__ a_d, float* __restrict__ as1,
                              float* __restrict__ ad1, int Nn) {
    int idx = blockIdx.x * 256 + threadIdx.x;   // n*8 + h
    if (idx >= Nn * NH1) return;
    int h = idx & 7;
    const float* hp = h1 + (size_t)(idx >> 3) * HC1 + h * 8;
    float s = 0.f, d = 0.f;
#pragma unroll
    for (int c = 0; c < 8; c++) {
        float v = hp[c];
        s += v * a_s[h * 8 + c];
        d += v * a_d[h * 8 + c];
    }
    as1[idx] = s;
    ad1[idx] = d;
}

__device__ __forceinline__ float lrelu(float e) { return e > 0.f ? e : NEG_SLOPE * e; }

// ---------------- layer-1 aggregation ----------------
__global__ __launch_bounds__(256) void agg1(const float* __restrict__ h1, const float* __restrict__ as1,
                                            const float* __restrict__ ad1, const int* __restrict__ rowptr,
                                            const int* __restrict__ col, const float* __restrict__ b1,
                                            float* __restrict__ h2, int Nn) {
    __shared__ float pbuf[4][NH1 * 68];
    int w = threadIdx.x >> 6;
    int wave = (blockIdx.x * 256 + threadIdx.x) >> 6;
    int lane = threadIdx.x & 63;
    if (wave >= Nn) return;
    int d = wave;
    int jb = rowptr[d], je = rowptr[d + 1];
    const float4* as4 = (const float4*)as1;
    const float4* ad4 = (const float4*)ad1;

    float4 sd0 = as4[d * 2], sd1 = as4[d * 2 + 1];
    float4 dd0 = ad4[d * 2], dd1 = ad4[d * 2 + 1];
    float ad[8] = {dd0.x, dd0.y, dd0.z, dd0.w, dd1.x, dd1.y, dd1.z, dd1.w};
    float sv[8] = {sd0.x, sd0.y, sd0.z, sd0.w, sd1.x, sd1.y, sd1.z, sd1.w};
    float e0[8];
#pragma unroll
    for (int h = 0; h < NH1; h++) e0[h] = lrelu(sv[h] + ad[h]);

    int myh = lane >> 3;
    float acc = h1[(size_t)d * HC1 + lane];    // self-loop, p = 1
    float ssum = 1.0f;
    float* pb = pbuf[w];

    for (int c0 = jb; c0 < je; c0 += 64) {
        int nc = min(64, je - c0);
        int srcv = d;
        if (lane < nc) srcv = col[c0 + lane];
        float4 a0 = as4[srcv * 2], a1 = as4[srcv * 2 + 1];
        float ev[8] = {a0.x, a0.y, a0.z, a0.w, a1.x, a1.y, a1.z, a1.w};
#pragma unroll
        for (int h = 0; h < NH1; h++)
            pb[h * 68 + lane] = __expf(lrelu(ev[h] + ad[h]) - e0[h]);

        int jj = 0;
        for (; jj + 3 < nc; jj += 4) {
            int s0 = __shfl(srcv, jj, 64), s1 = __shfl(srcv, jj + 1, 64);
            int s2 = __shfl(srcv, jj + 2, 64), s3 = __shfl(srcv, jj + 3, 64);
            float p0 = pb[myh * 68 + jj],     p1 = pb[myh * 68 + jj + 1];
            float p2 = pb[myh * 68 + jj + 2], p3 = pb[myh * 68 + jj + 3];
            float g0 = h1[(size_t)s0 * HC1 + lane];
            float g1 = h1[(size_t)s1 * HC1 + lane];
            float g2 = h1[(size_t)s2 * HC1 + lane];
            float g3 = h1[(size_t)s3 * HC1 + lane];
            ssum += (p0 + p1) + (p2 + p3);
            acc += p0 * g0 + p1 * g1 + p2 * g2 + p3 * g3;
        }
        for (; jj < nc; jj++) {
            int s0 = __shfl(srcv, jj, 64);
            float p0 = pb[myh * 68 + jj];
            ssum += p0;
            acc += p0 * h1[(size_t)s0 * HC1 + lane];
        }
    }
    float o = acc / (ssum + 1e-16f) + b1[lane];
    o = o > 0.f ? o : __expf(o) - 1.0f;     // ELU
    h2[(size_t)d * HC1 + lane] = o;
}

// ---------------- GEMM2 + alpha2 ----------------
__global__ __launch_bounds__(256) void gemm2(const float* __restrict__ h2, const float* __restrict__ W2,
                                             const float* __restrict__ av_in, const float* __restrict__ dv_in,
                                             float* __restrict__ g, float* __restrict__ as2,
                                             float* __restrict__ ad2, int Nn) {
    __shared__ float W2s[HC1 * NC];
    __shared__ float hrow[4][HC1];
    __shared__ float avec[NC], dvec[NC];
    int tid = threadIdx.x;
    for (int i = tid; i < HC1 * NC; i += 256) W2s[i] = W2[i];
    if (tid < NC) { avec[tid] = av_in[tid]; dvec[tid] = dv_in[tid]; }
    int w = tid >> 6, lane = tid & 63;
    int n = blockIdx.x * 4 + w;
    float hv = 0.f;
    if (n < Nn) hv = h2[(size_t)n * HC1 + lane];
    hrow[w][lane] = hv;
    __syncthreads();
    float acc = 0.f;
    bool act = (n < Nn) && (lane < NC);
    if (act) {
#pragma unroll
        for (int k = 0; k < HC1; k++) acc += hrow[w][k] * W2s[k * NC + lane];
        g[(size_t)n * NC + lane] = acc;
    }
    float va = act ? acc * avec[lane] : 0.f;
    float vd = act ? acc * dvec[lane] : 0.f;
    for (int off = 32; off; off >>= 1) {
        va += __shfl_xor(va, off, 64);
        vd += __shfl_xor(vd, off, 64);
    }
    if (n < Nn && lane == 0) { as2[n] = va; ad2[n] = vd; }
}

// ---------------- layer-2 aggregation + bias + log_softmax ----------------
__global__ __launch_bounds__(256) void agg2(const float* __restrict__ g, const float* __restrict__ as2,
                                            const float* __restrict__ ad2, const int* __restrict__ rowptr,
                                            const int* __restrict__ col, const float* __restrict__ b2,
                                            float* __restrict__ out, int Nn) {
    __shared__ float pbuf[4][64];
    int w = threadIdx.x >> 6;
    int wave = (blockIdx.x * 256 + threadIdx.x) >> 6;
    int lane = threadIdx.x & 63;
    if (wave >= Nn) return;
    int d = wave;
    int jb = rowptr[d], je = rowptr[d + 1];
    float adv = ad2[d];
    float e0 = lrelu(as2[d] + adv);
    float acc = (lane < NC) ? g[(size_t)d * NC + lane] : 0.f;   // self-loop p = 1
    float ssum = 1.0f;
    float* pb = pbuf[w];

    for (int c0 = jb; c0 < je; c0 += 64) {
        int nc = min(64, je - c0);
        int srcv = d;
        if (lane < nc) srcv = col[c0 + lane];
        pb[lane] = __expf(lrelu(as2[srcv] + adv) - e0);

        int jj = 0;
        for (; jj + 3 < nc; jj += 4) {
            int s0 = __shfl(srcv, jj, 64), s1 = __shfl(srcv, jj + 1, 64);
            int s2 = __shfl(srcv, jj + 2, 64), s3 = __shfl(srcv, jj + 3, 64);
            float p0 = pb[jj], p1 = pb[jj + 1], p2 = pb[jj + 2], p3 = pb[jj + 3];
            float g0 = 0.f, g1 = 0.f, g2 = 0.f, g3 = 0.f;
            if (lane < NC) {
                g0 = g[(size_t)s0 * NC + lane];
                g1 = g[(size_t)s1 * NC + lane];
                g2 = g[(size_t)s2 * NC + lane];
                g3 = g[(size_t)s3 * NC + lane];
            }
            ssum += (p0 + p1) + (p2 + p3);
            acc += p0 * g0 + p1 * g1 + p2 * g2 + p3 * g3;
        }
        for (; jj < nc; jj++) {
            int s0 = __shfl(srcv, jj, 64);
            float p0 = pb[jj];
            ssum += p0;
            if (lane < NC) acc += p0 * g[(size_t)s0 * NC + lane];
        }
    }
    float o = acc / (ssum + 1e-16f) + ((lane < NC) ? b2[lane] : 0.f);
    float vm = (lane < NC) ? o : -1e30f;
#pragma unroll
    for (int off = 32; off; off >>= 1) vm = fmaxf(vm, __shfl_xor(vm, off, 64));
    float ex = (lane < NC) ? __expf(o - vm) : 0.f;
#pragma unroll
    for (int off = 32; off; off >>= 1) ex += __shfl_xor(ex, off, 64);
    float lsm = o - vm - __logf(ex);
    if (lane < NC) out[(size_t)d * NC + lane] = lsm;
}

// ---------------- host launch ----------------
extern "C" void kernel_launch(void* const* d_in, const int* in_sizes, int n_in,
                              void* d_out, int out_size, void* d_ws, size_t ws_size,
                              hipStream_t stream) {
    const float* x      = (const float*)d_in[0];
    const int*   ei     = (const int*)d_in[1];
    const float* W1     = (const float*)d_in[2];
    const float* a_src1 = (const float*)d_in[3];
    const float* a_dst1 = (const float*)d_in[4];
    const float* b1     = (const float*)d_in[5];
    const float* W2     = (const float*)d_in[6];
    const float* a_src2 = (const float*)d_in[7];
    const float* a_dst2 = (const float*)d_in[8];
    const float* b2     = (const float*)d_in[9];
    float* out = (float*)d_out;

    const int N = in_sizes[0] / F_IN;       // 100000
    const int E = in_sizes[1] / 2;          // 1600000
    const int NB = (N + 255) >> 8;          // 256-node buckets

    char* p = (char*)d_ws;
    auto alloc = [&](size_t bytes) -> void* {
        void* r = (void*)p;
        p += (bytes + 255) & ~(size_t)255;
        return r;
    };
    int2* pairs = (int2*)alloc((size_t)E * 8);
    int* deg    = (int*)alloc((size_t)N * 4);
    int* rowptr = (int*)alloc(((size_t)N + 1) * 4);
    int* bcur   = (int*)alloc((size_t)MAXNB * 4);
    int* bsums  = (int*)alloc(64 * 4);
    int* flag   = (int*)alloc(256);
    int* col    = (int*)alloc((size_t)E * 4);
    float* h1   = (float*)alloc((size_t)N * HC1 * 4);   // reused as g
    float* as1  = (float*)alloc((size_t)N * NH1 * 4);   // reused as as2
    float* ad1  = (float*)alloc((size_t)N * NH1 * 4);   // reused as ad2
    float* h2   = (float*)alloc((size_t)N * HC1 * 4);
    float* g    = h1;
    float* as2  = as1;
    float* ad2  = ad1;

    // --- CSR build ---
    hipMemsetAsync(deg, 0, (size_t)N * 4, stream);
    detect_i64<<<1, 256, 0, stream>>>(ei, flag, 4096);
    int ge = (E + 255) / 256;
    hist_kernel<<<ge, 256, 0, stream>>>(ei, flag, deg, E);
    int nb = (N + SCAN_CHUNK - 1) / SCAN_CHUNK;
    scan1<<<nb, 256, 0, stream>>>(deg, rowptr, bsums, N);
    scan2<<<1, 64, 0, stream>>>(bsums, nb);
    scan3<<<(N + 255) / 256, 256, 0, stream>>>(deg, rowptr, bcur, bsums, N);
    scatter1<<<(E + RADIX_EPB - 1) / RADIX_EPB, 256, 0, stream>>>(ei, flag, bcur, pairs, E, NB);
    scatter2<<<NB, 256, 0, stream>>>(pairs, rowptr, col, N);

    // --- layer 1 ---
    gemm1<<<(N + 63) / 64, 256, 0, stream>>>(x, W1, h1, N);
    alpha1_kernel<<<(N * NH1 + 255) / 256, 256, 0, stream>>>(h1, a_src1, a_dst1, as1, ad1, N);
    agg1<<<(N + 3) / 4, 256, 0, stream>>>(h1, as1, ad1, rowptr, col, b1, h2, N);

    // --- layer 2 ---
    gemm2<<<(N + 3) / 4, 256, 0, stream>>>(h2, W2, a_src2, a_dst2, g, as2, ad2, N);
    agg2<<<(N + 3) / 4, 256, 0, stream>>>(g, as2, ad2, rowptr, col, b2, out, N);
}

// Round 5
// 639.110 us; speedup vs baseline: 1.5096x; 1.0474x over previous
//
#include <hip/hip_runtime.h>
#include <hip/hip_bf16.h>

// ---------------- problem constants (from reference) ----------------
// N = 100000 nodes, E = 1600000 edges, F_IN = 512, H1*C1 = 64, NUM_CLASSES = 40
#define F_IN 512
#define HC1 64          // 8 heads * 8 ch
#define NH1 8
#define NC 40
#define NEG_SLOPE 0.2f
#define SCAN_CHUNK 2048
#define RADIX_EPB 4096  // edges per block in scatter1
#define MAXNB 512       // max node buckets (256 nodes each)

typedef short bf16x8 __attribute__((ext_vector_type(8)));
typedef float f32x4 __attribute__((ext_vector_type(4)));

static __device__ __forceinline__ unsigned short f2b(float f) {
    __hip_bfloat16 h = __float2bfloat16(f);      // RNE
    return *(unsigned short*)&h;
}
static __device__ __forceinline__ float b2f(unsigned short u) {
    union { unsigned int i; float f; } v;
    v.i = ((unsigned int)u) << 16;               // bf16 -> fp32 exact
    return v.f;
}

// ---------------- edge-index dtype detection ----------------
__global__ void detect_i64(const int* __restrict__ ei, int* __restrict__ flag, int n_check) {
    __shared__ int found;
    if (threadIdx.x == 0) found = 0;
    __syncthreads();
    for (int i = threadIdx.x; i < n_check; i += 256) {
        if (ei[2 * i + 1] != 0) atomicOr(&found, 1);
    }
    __syncthreads();
    if (threadIdx.x == 0) *flag = (found == 0) ? 1 : 0;   // 1 => int64
}

// degree histogram: reads only the dst half of edge_index
__global__ void hist_kernel(const int* __restrict__ ei, const int* __restrict__ flag,
                            int* __restrict__ deg, int E) {
    int e = blockIdx.x * 256 + threadIdx.x;
    if (e >= E) return;
    int f = *flag;
    int d = f ? ei[2 * (E + e)] : ei[E + e];
    atomicAdd(&deg[d], 1);
}

// ---------------- CSR build: scans ----------------
__global__ __launch_bounds__(256) void scan1(const int* __restrict__ deg, int* __restrict__ rowptr,
                                             int* __restrict__ bsums, int n) {
    __shared__ int sbuf[256];
    int tid = threadIdx.x;
    int base = blockIdx.x * SCAN_CHUNK + tid * 8;
    int v[8];
#pragma unroll
    for (int j = 0; j < 8; j++) { int idx = base + j; v[j] = (idx < n) ? deg[idx] : 0; }
    int tsum = 0;
#pragma unroll
    for (int j = 0; j < 8; j++) tsum += v[j];
    sbuf[tid] = tsum;
    __syncthreads();
    for (int off = 1; off < 256; off <<= 1) {
        int t = (tid >= off) ? sbuf[tid - off] : 0;
        __syncthreads();
        sbuf[tid] += t;
        __syncthreads();
    }
    int run = sbuf[tid] - tsum;
#pragma unroll
    for (int j = 0; j < 8; j++) {
        run += v[j];
        int idx = base + j;
        if (idx < n) rowptr[1 + idx] = run;
    }
    if (tid == 255) bsums[blockIdx.x] = sbuf[255];
}

__global__ void scan2(int* __restrict__ bsums, int nb) {
    int lane = threadIdx.x & 63;
    int v = (lane < nb) ? bsums[lane] : 0;
    int orig = v;
    for (int off = 1; off < 64; off <<= 1) {
        int t = __shfl_up(v, (unsigned)off, 64);
        if (lane >= off) v += t;
    }
    if (lane < nb) bsums[lane] = v - orig;
}

__global__ void scan3(const int* __restrict__ deg, int* __restrict__ rowptr,
                      int* __restrict__ bcur, const int* __restrict__ bsums, int n) {
    int i = blockIdx.x * 256 + threadIdx.x;
    if (i >= n) return;
    int off = bsums[i >> 11];
    int incl = rowptr[1 + i] + off;
    rowptr[1 + i] = incl;
    if ((i & 255) == 0) bcur[i >> 8] = incl - deg[i];
    if (i == 0) rowptr[0] = 0;
}

// ---------------- scatter pass 1: block-binned append into 256-node buckets --------
__global__ __launch_bounds__(256) void scatter1(const int* __restrict__ ei, const int* __restrict__ flag,
                                                int* __restrict__ bcur, int2* __restrict__ pairs,
                                                int E, int NB) {
    __shared__ int cnt[MAXNB];
    __shared__ int gb[MAXNB];
    int tid = threadIdx.x;
    for (int i = tid; i < NB; i += 256) cnt[i] = 0;
    __syncthreads();
    int f = *flag;
    int base = blockIdx.x * RADIX_EPB;
    int sv[16], dv[16], rv[16];
#pragma unroll
    for (int i = 0; i < 16; i++) {
        int e = base + i * 256 + tid;
        if (e < E) {
            int s, d;
            if (f) { s = ei[2 * e]; d = ei[2 * (E + e)]; }
            else   { s = ei[e];     d = ei[E + e]; }
            sv[i] = s; dv[i] = d;
            rv[i] = atomicAdd(&cnt[d >> 8], 1);
        }
    }
    __syncthreads();
    for (int i = tid; i < NB; i += 256) {
        int c = cnt[i];
        gb[i] = c ? atomicAdd(&bcur[i], c) : 0;
    }
    __syncthreads();
#pragma unroll
    for (int i = 0; i < 16; i++) {
        int e = base + i * 256 + tid;
        if (e < E) {
            int pos = gb[dv[i] >> 8] + rv[i];
            pairs[pos] = make_int2(sv[i], dv[i]);
        }
    }
}

// ---------------- scatter pass 2: per-bucket finalize (LDS cursors) ----------------
__global__ __launch_bounds__(256) void scatter2(const int2* __restrict__ pairs,
                                                const int* __restrict__ rowptr,
                                                int* __restrict__ col, int Nn) {
    __shared__ int cur[256];
    int b = blockIdx.x;
    int node0 = b << 8;
    int tid = threadIdx.x;
    int nlast = min(node0 + 256, Nn);
    if (node0 + tid < nlast) cur[tid] = rowptr[node0 + tid];
    __syncthreads();
    int jb = rowptr[node0];
    int je = rowptr[nlast];
    for (int j = jb + tid; j < je; j += 256) {
        int2 pr = pairs[j];
        int pos = atomicAdd(&cur[pr.y - node0], 1);
        col[pos] = pr.x;
    }
}

// ---------------- GEMM1 (bf16 MFMA) + fused alpha1 ----------------
// h1[N,64](bf16) = x[N,512] @ W1[512,64]; as1/ad1[N,8] = per-head dots.
// Block: 64 output rows, 4 waves; wave w = rows [w*16, w*16+16) x all 64 cols.
// mfma_f32_16x16x32_bf16: A[m=lane&15][k=quad*8+j]; B[k=quad*8+j][n=lane&15];
// D: col=lane&15, row=quad*4+reg.
__global__ __launch_bounds__(256) void gemm1(const float* __restrict__ x, const float* __restrict__ W,
                                             const float* __restrict__ a_s, const float* __restrict__ a_d,
                                             unsigned short* __restrict__ h1, float* __restrict__ as1,
                                             float* __restrict__ ad1, int Nn) {
    __shared__ unsigned short xs[64][72];    // rows x k (pad 8 -> 144B stride, 2-way max)
    __shared__ unsigned short wsT[64][72];   // n x k (transposed for contiguous B frags)
    int tid = threadIdx.x;
    int m0 = blockIdx.x * 64;
    int w = tid >> 6, lane = tid & 63;
    int quad = lane >> 4, mr = lane & 15;
    f32x4 acc[4];
#pragma unroll
    for (int i = 0; i < 4; i++) acc[i] = (f32x4){0.f, 0.f, 0.f, 0.f};

    int lrow = tid >> 4;        // 0..15
    int lf4 = tid & 15;         // float4 slot within 64-wide k chunk

    for (int k0 = 0; k0 < F_IN; k0 += 64) {
        float4 xv[4], wv[4];
#pragma unroll
        for (int i = 0; i < 4; i++) {
            int row = i * 16 + lrow;
            xv[i] = (m0 + row < Nn) ? *(const float4*)(x + (size_t)(m0 + row) * F_IN + k0 + lf4 * 4)
                                    : make_float4(0.f, 0.f, 0.f, 0.f);
            wv[i] = *(const float4*)(W + (size_t)(k0 + row) * HC1 + lf4 * 4);
        }
        __syncthreads();   // previous iteration's MFMA reads complete
#pragma unroll
        for (int i = 0; i < 4; i++) {
            int row = i * 16 + lrow;
            xs[row][lf4 * 4 + 0] = f2b(xv[i].x);
            xs[row][lf4 * 4 + 1] = f2b(xv[i].y);
            xs[row][lf4 * 4 + 2] = f2b(xv[i].z);
            xs[row][lf4 * 4 + 3] = f2b(xv[i].w);
            wsT[lf4 * 4 + 0][row] = f2b(wv[i].x);
            wsT[lf4 * 4 + 1][row] = f2b(wv[i].y);
            wsT[lf4 * 4 + 2][row] = f2b(wv[i].z);
            wsT[lf4 * 4 + 3][row] = f2b(wv[i].w);
        }
        __syncthreads();
#pragma unroll
        for (int ks = 0; ks < 2; ks++) {
            bf16x8 a = *(const bf16x8*)&xs[w * 16 + mr][ks * 32 + quad * 8];
#pragma unroll
            for (int nb = 0; nb < 4; nb++) {
                bf16x8 b = *(const bf16x8*)&wsT[nb * 16 + mr][ks * 32 + quad * 8];
                acc[nb] = __builtin_amdgcn_mfma_f32_16x16x32_bf16(a, b, acc[nb], 0, 0, 0);
            }
        }
    }
    __syncthreads();
    // D -> LDS tile (reuse xs as hs[64][72])
    unsigned short (*hs)[72] = xs;
#pragma unroll
    for (int nb = 0; nb < 4; nb++)
#pragma unroll
        for (int r = 0; r < 4; r++)
            hs[w * 16 + quad * 4 + r][nb * 16 + mr] = f2b(acc[nb][r]);
    __syncthreads();
    // coalesced bf16 store: thread -> 32B (16 elems)
    {
        int srow = tid >> 2, sseg = tid & 3;
        if (m0 + srow < Nn) {
            uint4 v0 = *(const uint4*)&hs[srow][sseg * 16];
            uint4 v1 = *(const uint4*)&hs[srow][sseg * 16 + 8];
            uint4* dst = (uint4*)(h1 + (size_t)(m0 + srow) * HC1 + sseg * 16);
            dst[0] = v0;
            dst[1] = v1;
        }
    }
    // fused alpha1: 512 (row,head) pairs per block
    for (int i = tid; i < 512; i += 256) {
        int row = i >> 3, hh = i & 7;
        if (m0 + row < Nn) {
            float s = 0.f, d = 0.f;
#pragma unroll
            for (int c = 0; c < 8; c++) {
                float v = b2f(hs[row][hh * 8 + c]);
                s += v * a_s[hh * 8 + c];
                d += v * a_d[hh * 8 + c];
            }
            as1[(size_t)(m0 + row) * NH1 + hh] = s;
            ad1[(size_t)(m0 + row) * NH1 + hh] = d;
        }
    }
}

__device__ __forceinline__ float lrelu(float e) { return e > 0.f ? e : NEG_SLOPE * e; }

// ---------------- layer-1 aggregation (h1 in bf16) ----------------
__global__ __launch_bounds__(256) void agg1(const unsigned short* __restrict__ h1,
                                            const float* __restrict__ as1,
                                            const float* __restrict__ ad1, const int* __restrict__ rowptr,
                                            const int* __restrict__ col, const float* __restrict__ b1,
                                            float* __restrict__ h2, int Nn) {
    __shared__ float pbuf[4][NH1 * 68];
    int w = threadIdx.x >> 6;
    int wave = (blockIdx.x * 256 + threadIdx.x) >> 6;
    int lane = threadIdx.x & 63;
    if (wave >= Nn) return;
    int d = wave;
    int jb = rowptr[d], je = rowptr[d + 1];
    const float4* as4 = (const float4*)as1;
    const float4* ad4 = (const float4*)ad1;

    float4 sd0 = as4[d * 2], sd1 = as4[d * 2 + 1];
    float4 dd0 = ad4[d * 2], dd1 = ad4[d * 2 + 1];
    float ad[8] = {dd0.x, dd0.y, dd0.z, dd0.w, dd1.x, dd1.y, dd1.z, dd1.w};
    float sv[8] = {sd0.x, sd0.y, sd0.z, sd0.w, sd1.x, sd1.y, sd1.z, sd1.w};
    float e0[8];
#pragma unroll
    for (int h = 0; h < NH1; h++) e0[h] = lrelu(sv[h] + ad[h]);

    int myh = lane >> 3;
    float acc = b2f(h1[(size_t)d * HC1 + lane]);   // self-loop, p = 1
    float ssum = 1.0f;
    float* pb = pbuf[w];

    for (int c0 = jb; c0 < je; c0 += 64) {
        int nc = min(64, je - c0);
        int srcv = d;
        if (lane < nc) srcv = col[c0 + lane];
        float4 a0 = as4[srcv * 2], a1 = as4[srcv * 2 + 1];
        float ev[8] = {a0.x, a0.y, a0.z, a0.w, a1.x, a1.y, a1.z, a1.w};
#pragma unroll
        for (int h = 0; h < NH1; h++)
            pb[h * 68 + lane] = __expf(lrelu(ev[h] + ad[h]) - e0[h]);

        int jj = 0;
        for (; jj + 3 < nc; jj += 4) {
            int s0 = __shfl(srcv, jj, 64), s1 = __shfl(srcv, jj + 1, 64);
            int s2 = __shfl(srcv, jj + 2, 64), s3 = __shfl(srcv, jj + 3, 64);
            float p0 = pb[myh * 68 + jj],     p1 = pb[myh * 68 + jj + 1];
            float p2 = pb[myh * 68 + jj + 2], p3 = pb[myh * 68 + jj + 3];
            float g0 = b2f(h1[(size_t)s0 * HC1 + lane]);
            float g1 = b2f(h1[(size_t)s1 * HC1 + lane]);
            float g2 = b2f(h1[(size_t)s2 * HC1 + lane]);
            float g3 = b2f(h1[(size_t)s3 * HC1 + lane]);
            ssum += (p0 + p1) + (p2 + p3);
            acc += p0 * g0 + p1 * g1 + p2 * g2 + p3 * g3;
        }
        for (; jj < nc; jj++) {
            int s0 = __shfl(srcv, jj, 64);
            float p0 = pb[myh * 68 + jj];
            ssum += p0;
            acc += p0 * b2f(h1[(size_t)s0 * HC1 + lane]);
        }
    }
    float o = acc / (ssum + 1e-16f) + b1[lane];
    o = o > 0.f ? o : __expf(o) - 1.0f;     // ELU
    h2[(size_t)d * HC1 + lane] = o;
}

// ---------------- GEMM2 + alpha2 ----------------
__global__ __launch_bounds__(256) void gemm2(const float* __restrict__ h2, const float* __restrict__ W2,
                                             const float* __restrict__ av_in, const float* __restrict__ dv_in,
                                             float* __restrict__ g, float* __restrict__ as2,
                                             float* __restrict__ ad2, int Nn) {
    __shared__ float W2s[HC1 * NC];
    __shared__ float hrow[4][HC1];
    __shared__ float avec[NC], dvec[NC];
    int tid = threadIdx.x;
    for (int i = tid; i < HC1 * NC; i += 256) W2s[i] = W2[i];
    if (tid < NC) { avec[tid] = av_in[tid]; dvec[tid] = dv_in[tid]; }
    int w = tid >> 6, lane = tid & 63;
    int n = blockIdx.x * 4 + w;
    float hv = 0.f;
    if (n < Nn) hv = h2[(size_t)n * HC1 + lane];
    hrow[w][lane] = hv;
    __syncthreads();
    float acc = 0.f;
    bool act = (n < Nn) && (lane < NC);
    if (act) {
#pragma unroll
        for (int k = 0; k < HC1; k++) acc += hrow[w][k] * W2s[k * NC + lane];
        g[(size_t)n * NC + lane] = acc;
    }
    float va = act ? acc * avec[lane] : 0.f;
    float vd = act ? acc * dvec[lane] : 0.f;
    for (int off = 32; off; off >>= 1) {
        va += __shfl_xor(va, off, 64);
        vd += __shfl_xor(vd, off, 64);
    }
    if (n < Nn && lane == 0) { as2[n] = va; ad2[n] = vd; }
}

// ---------------- layer-2 aggregation + bias + log_softmax ----------------
__global__ __launch_bounds__(256) void agg2(const float* __restrict__ g, const float* __restrict__ as2,
                                            const float* __restrict__ ad2, const int* __restrict__ rowptr,
                                            const int* __restrict__ col, const float* __restrict__ b2,
                                            float* __restrict__ out, int Nn) {
    __shared__ float pbuf[4][64];
    int w = threadIdx.x >> 6;
    int wave = (blockIdx.x * 256 + threadIdx.x) >> 6;
    int lane = threadIdx.x & 63;
    if (wave >= Nn) return;
    int d = wave;
    int jb = rowptr[d], je = rowptr[d + 1];
    float adv = ad2[d];
    float e0 = lrelu(as2[d] + adv);
    float acc = (lane < NC) ? g[(size_t)d * NC + lane] : 0.f;   // self-loop p = 1
    float ssum = 1.0f;
    float* pb = pbuf[w];

    for (int c0 = jb; c0 < je; c0 += 64) {
        int nc = min(64, je - c0);
        int srcv = d;
        if (lane < nc) srcv = col[c0 + lane];
        pb[lane] = __expf(lrelu(as2[srcv] + adv) - e0);

        int jj = 0;
        for (; jj + 3 < nc; jj += 4) {
            int s0 = __shfl(srcv, jj, 64), s1 = __shfl(srcv, jj + 1, 64);
            int s2 = __shfl(srcv, jj + 2, 64), s3 = __shfl(srcv, jj + 3, 64);
            float p0 = pb[jj], p1 = pb[jj + 1], p2 = pb[jj + 2], p3 = pb[jj + 3];
            float g0 = 0.f, g1 = 0.f, g2 = 0.f, g3 = 0.f;
            if (lane < NC) {
                g0 = g[(size_t)s0 * NC + lane];
                g1 = g[(size_t)s1 * NC + lane];
                g2 = g[(size_t)s2 * NC + lane];
                g3 = g[(size_t)s3 * NC + lane];
            }
            ssum += (p0 + p1) + (p2 + p3);
            acc += p0 * g0 + p1 * g1 + p2 * g2 + p3 * g3;
        }
        for (; jj < nc; jj++) {
            int s0 = __shfl(srcv, jj, 64);
            float p0 = pb[jj];
            ssum += p0;
            if (lane < NC) acc += p0 * g[(size_t)s0 * NC + lane];
        }
    }
    float o = acc / (ssum + 1e-16f) + ((lane < NC) ? b2[lane] : 0.f);
    float vm = (lane < NC) ? o : -1e30f;
#pragma unroll
    for (int off = 32; off; off >>= 1) vm = fmaxf(vm, __shfl_xor(vm, off, 64));
    float ex = (lane < NC) ? __expf(o - vm) : 0.f;
#pragma unroll
    for (int off = 32; off; off >>= 1) ex += __shfl_xor(ex, off, 64);
    float lsm = o - vm - __logf(ex);
    if (lane < NC) out[(size_t)d * NC + lane] = lsm;
}

// ---------------- host launch ----------------
extern "C" void kernel_launch(void* const* d_in, const int* in_sizes, int n_in,
                              void* d_out, int out_size, void* d_ws, size_t ws_size,
                              hipStream_t stream) {
    const float* x      = (const float*)d_in[0];
    const int*   ei     = (const int*)d_in[1];
    const float* W1     = (const float*)d_in[2];
    const float* a_src1 = (const float*)d_in[3];
    const float* a_dst1 = (const float*)d_in[4];
    const float* b1     = (const float*)d_in[5];
    const float* W2     = (const float*)d_in[6];
    const float* a_src2 = (const float*)d_in[7];
    const float* a_dst2 = (const float*)d_in[8];
    const float* b2     = (const float*)d_in[9];
    float* out = (float*)d_out;

    const int N = in_sizes[0] / F_IN;       // 100000
    const int E = in_sizes[1] / 2;          // 1600000
    const int NB = (N + 255) >> 8;          // 256-node buckets

    char* p = (char*)d_ws;
    auto alloc = [&](size_t bytes) -> void* {
        void* r = (void*)p;
        p += (bytes + 255) & ~(size_t)255;
        return r;
    };
    int2* pairs = (int2*)alloc((size_t)E * 8);
    int* deg    = (int*)alloc((size_t)N * 4);
    int* rowptr = (int*)alloc(((size_t)N + 1) * 4);
    int* bcur   = (int*)alloc((size_t)MAXNB * 4);
    int* bsums  = (int*)alloc(64 * 4);
    int* flag   = (int*)alloc(256);
    int* col    = (int*)alloc((size_t)E * 4);
    unsigned short* h1 = (unsigned short*)alloc((size_t)N * HC1 * 4); // bf16; buffer reused as g (fp32 N*40)
    float* as1  = (float*)alloc((size_t)N * NH1 * 4);   // reused as as2
    float* ad1  = (float*)alloc((size_t)N * NH1 * 4);   // reused as ad2
    float* h2   = (float*)alloc((size_t)N * HC1 * 4);
    float* g    = (float*)h1;
    float* as2  = as1;
    float* ad2  = ad1;

    // --- CSR build ---
    hipMemsetAsync(deg, 0, (size_t)N * 4, stream);
    detect_i64<<<1, 256, 0, stream>>>(ei, flag, 4096);
    int ge = (E + 255) / 256;
    hist_kernel<<<ge, 256, 0, stream>>>(ei, flag, deg, E);
    int nb = (N + SCAN_CHUNK - 1) / SCAN_CHUNK;
    scan1<<<nb, 256, 0, stream>>>(deg, rowptr, bsums, N);
    scan2<<<1, 64, 0, stream>>>(bsums, nb);
    scan3<<<(N + 255) / 256, 256, 0, stream>>>(deg, rowptr, bcur, bsums, N);
    scatter1<<<(E + RADIX_EPB - 1) / RADIX_EPB, 256, 0, stream>>>(ei, flag, bcur, pairs, E, NB);
    scatter2<<<NB, 256, 0, stream>>>(pairs, rowptr, col, N);

    // --- layer 1 (gemm1 fuses alpha1) ---
    gemm1<<<(N + 63) / 64, 256, 0, stream>>>(x, W1, a_src1, a_dst1, h1, as1, ad1, N);
    agg1<<<(N + 3) / 4, 256, 0, stream>>>(h1, as1, ad1, rowptr, col, b1, h2, N);

    // --- layer 2 ---
    gemm2<<<(N + 3) / 4, 256, 0, stream>>>(h2, W2, a_src2, a_dst2, g, as2, ad2, N);
    agg2<<<(N + 3) / 4, 256, 0, stream>>>(g, as2, ad2, rowptr, col, b2, out, N);
}